// Round 13
// baseline (341.373 us; speedup 1.0000x reference)
//
#include <hip/hip_runtime.h>

#define NN 100000
#define NE 3200000
#define DIN 128
#define HD 32
#define MID 16
#define OUTD 8
#define LN_EPS 1e-5f

#define BINSHIFT 8                 // 256 nodes per bin
#define NB 391                     // ceil(NN / 256)
#define CAP 10240                  // bin capacity (mean 8192)
#define EPB 8192                   // edges per pass-A block
#define ABS 1024                   // pass-A block size (16 waves/block)
#define AITER (EPB / ABS)          // 8
#define CBS 1024                   // pass-C block size

// true clang vector types (required by __builtin_nontemporal_*)
typedef int   int4_v   __attribute__((ext_vector_type(4)));
typedef float float4_v __attribute__((ext_vector_type(4)));

// ---------------- bf16 helpers ----------------

__device__ __forceinline__ float bf2f(unsigned short u) {
    union { unsigned int i; float f; } c;
    c.i = ((unsigned int)u) << 16;
    return c.f;
}
__device__ __forceinline__ unsigned short f2bf(float f) {
    union { float f; unsigned int i; } c;
    c.f = f;
    unsigned int r = c.i + 0x7FFFu + ((c.i >> 16) & 1u);  // RNE
    return (unsigned short)(r >> 16);
}
__device__ __forceinline__ unsigned int pack2(float a, float b) {
    return (unsigned int)f2bf(a) | ((unsigned int)f2bf(b) << 16);
}
__device__ __forceinline__ void addpk(float& a0, float& a1, unsigned int u) {
    union { unsigned int i; float f; } lo, hi;
    lo.i = u << 16;
    hi.i = u & 0xFFFF0000u;
    a0 += lo.f;
    a1 += hi.f;
}

// ---------------- binned CSR build ----------------

__global__ void k_zero_bins(int* __restrict__ g_bincur) {
    int i = blockIdx.x * blockDim.x + threadIdx.x;
    if (i < NB) g_bincur[i] = 0;
}

// Pass A with LDS regroup: histogram -> scan -> pack edges bin-contiguously in
// LDS -> coalesced run writes to global staging.
__global__ __launch_bounds__(ABS) void k_binA(const int* __restrict__ src,
                                              const int* __restrict__ dst,
                                              int* __restrict__ g_bincur,
                                              unsigned int* __restrict__ staged) {
    __shared__ int cnt[512];              // histogram -> cursor
    __shared__ int obin[512];             // intra-block exclusive offsets
    __shared__ int base[NB];              // global reserved base per bin
    __shared__ unsigned short sbin[EPB];  // slot -> bin
    __shared__ unsigned int sedge[EPB];   // packed edges, bin-grouped
    int tid = threadIdx.x;
    if (tid < 512) cnt[tid] = 0;
    __syncthreads();
    int e0 = blockIdx.x * EPB;
    int total = min(EPB, NE - e0);
    int dreg[AITER];
#pragma unroll
    for (int i = 0; i < AITER; ++i) {
        int e = e0 + i * ABS + tid;
        dreg[i] = (e < NE) ? dst[e] : -1;
        if (dreg[i] >= 0) atomicAdd(&cnt[dreg[i] >> BINSHIFT], 1);
    }
    __syncthreads();
    // exclusive scan over 512 bins
    int v = 0;
    if (tid < 512) {
        v = cnt[tid];
        obin[tid] = v;
    }
    __syncthreads();
#pragma unroll
    for (int off = 1; off < 512; off <<= 1) {
        int t = (tid < 512 && tid >= off) ? obin[tid - off] : 0;
        __syncthreads();
        if (tid < 512) obin[tid] += t;
        __syncthreads();
    }
    if (tid < 512) obin[tid] -= v;  // exclusive
    __syncthreads();
    // reserve global space, fill slot->bin map, reset cursors
    if (tid < NB) {
        int c = cnt[tid];
        base[tid] = c ? atomicAdd(&g_bincur[tid], c) : 0;
        int s0 = obin[tid];
        for (int k = 0; k < c; ++k) sbin[s0 + k] = (unsigned short)tid;
    }
    if (tid < 512) cnt[tid] = 0;
    __syncthreads();
    // place edges into LDS grouped by bin
#pragma unroll
    for (int i = 0; i < AITER; ++i) {
        int e = e0 + i * ABS + tid;
        int d = dreg[i];
        if (d >= 0) {
            int b = d >> BINSHIFT;
            int slot = obin[b] + atomicAdd(&cnt[b], 1);
            sedge[slot] = ((unsigned int)(d & 255) << 24) | (unsigned int)src[e];
        }
    }
    __syncthreads();
    // coalesced write-out: consecutive threads -> consecutive slots
#pragma unroll
    for (int i = 0; i < AITER; ++i) {
        int s = i * ABS + tid;
        if (s < total) {
            int b = sbin[s];
            int k = base[b] + (s - obin[b]);
            if (k < CAP) staged[(size_t)b * CAP + k] = sedge[s];
        }
    }
}

__global__ void k_binscan(const int* __restrict__ g_bincur, int* __restrict__ g_binexcl,
                          int* __restrict__ row_ptr) {
    __shared__ int s[512];
    int v = (threadIdx.x < NB) ? min(g_bincur[threadIdx.x], CAP) : 0;
    s[threadIdx.x] = v;
    __syncthreads();
#pragma unroll
    for (int off = 1; off < 512; off <<= 1) {
        int t = (threadIdx.x >= off) ? s[threadIdx.x - off] : 0;
        __syncthreads();
        s[threadIdx.x] += t;
        __syncthreads();
    }
    if (threadIdx.x < NB) g_binexcl[threadIdx.x] = s[threadIdx.x] - v;
    if (threadIdx.x == NB - 1) row_ptr[NN] = s[threadIdx.x];
}

__global__ __launch_bounds__(CBS) void k_binC(const int* __restrict__ g_bincur,
                                              const int* __restrict__ g_binexcl,
                                              const unsigned int* __restrict__ staged,
                                              int* __restrict__ row_ptr,
                                              float* __restrict__ dis,
                                              int* __restrict__ csr_src) {
    __shared__ int cnt[256];
    __shared__ int scn[256];
    int b = blockIdx.x;
    int tid = threadIdx.x;
    int tot = min(g_bincur[b], CAP);
    if (tid < 256) cnt[tid] = 0;
    __syncthreads();
    const unsigned int* st = staged + (size_t)b * CAP;
    for (int i = tid; i < tot; i += CBS)
        atomicAdd(&cnt[st[i] >> 24], 1);
    __syncthreads();
    int v = 0;
    if (tid < 256) {
        v = cnt[tid];
        scn[tid] = v;
    }
    __syncthreads();
#pragma unroll
    for (int off = 1; off < 256; off <<= 1) {
        int t = (tid < 256 && tid >= off) ? scn[tid - off] : 0;
        __syncthreads();
        if (tid < 256) scn[tid] += t;
        __syncthreads();
    }
    int gbase = g_binexcl[b];
    if (tid < 256) {
        int excl = scn[tid] - v;
        int node = (b << BINSHIFT) + tid;
        if (node < NN) {
            row_ptr[node] = gbase + excl;
            dis[node] = rsqrtf((float)(v + 1));  // +1 self-loop
        }
        cnt[tid] = excl;  // reuse as scatter cursor
    }
    __syncthreads();
    for (int i = tid; i < tot; i += CBS) {
        unsigned int p = st[i];
        int rank = atomicAdd(&cnt[p >> 24], 1);
        csr_src[gbase + rank] = (int)(p & 0xFFFFFFu);
    }
}

// ---------------- GEMM: block = 64 nodes x 4 waves; W staged in LDS ----------------

template <int K>
__global__ __launch_bounds__(256) void k_gemm(const float* __restrict__ x,
                                              const float* __restrict__ W,
                                              const float* __restrict__ dis,
                                              unsigned short* __restrict__ hs) {
    __shared__ float sW[K * HD];
    for (int t = threadIdx.x; t < K * HD; t += 256) sW[t] = W[t];
    __syncthreads();
    int lane = threadIdx.x & 63;
    int q = __builtin_amdgcn_readfirstlane(threadIdx.x >> 6);  // 0..3, SGPR
    int n = blockIdx.x * 64 + lane;
    if (n >= NN) return;
    const float* xr = x + (size_t)n * K;
    const float* Wq = sW + q * 8;
    float acc[8];
#pragma unroll
    for (int j = 0; j < 8; ++j) acc[j] = 0.f;
    for (int k0 = 0; k0 < K; k0 += 4) {
        float4_v xv = __builtin_nontemporal_load(
            reinterpret_cast<const float4_v*>(xr + k0));  // read-once stream
#pragma unroll
        for (int kk = 0; kk < 4; ++kk) {
            float xk = xv[kk];
#pragma unroll
            for (int j = 0; j < 8; ++j)
                acc[j] = fmaf(xk, Wq[(k0 + kk) * HD + j], acc[j]);
        }
    }
    float d = dis[n];
    uint4 p;
    p.x = pack2(acc[0] * d, acc[1] * d);
    p.y = pack2(acc[2] * d, acc[3] * d);
    p.z = pack2(acc[4] * d, acc[5] * d);
    p.w = pack2(acc[6] * d, acc[7] * d);
    *reinterpret_cast<uint4*>(hs + (size_t)n * HD + q * 8) = p;  // keep cached
}

// ---------------- gather: 8 lanes/node, 4 ch/lane; nt streams ----------------

#define G4(si) \
    { \
        uint2 g0 = *reinterpret_cast<const uint2*>(h + (size_t)(si).x * HD + c0); \
        uint2 g1 = *reinterpret_cast<const uint2*>(h + (size_t)(si).y * HD + c0); \
        uint2 g2 = *reinterpret_cast<const uint2*>(h + (size_t)(si).z * HD + c0); \
        uint2 g3 = *reinterpret_cast<const uint2*>(h + (size_t)(si).w * HD + c0); \
        addpk(a0, a1, g0.x); addpk(a2, a3, g0.y); \
        addpk(a0, a1, g1.x); addpk(a2, a3, g1.y); \
        addpk(a0, a1, g2.x); addpk(a2, a3, g2.y); \
        addpk(a0, a1, g3.x); addpk(a2, a3, g3.y); \
    }

template <int DO_LN>
__global__ __launch_bounds__(256) void k_gather(
        const int* __restrict__ row_ptr, const int* __restrict__ csr_src,
        const float* __restrict__ dis, const unsigned short* __restrict__ h,
        const float* __restrict__ bias, const float* __restrict__ g,
        const float* __restrict__ bln, float* __restrict__ out) {
    int idx = blockIdx.x * blockDim.x + threadIdx.x;
    int n = idx >> 3, sub = idx & 7;
    if (n >= NN) return;
    int c0 = sub << 2;

    uint2 u = *reinterpret_cast<const uint2*>(h + (size_t)n * HD + c0);  // self-loop
    float a0 = 0.f, a1 = 0.f, a2 = 0.f, a3 = 0.f;
    addpk(a0, a1, u.x);
    addpk(a2, a3, u.y);

    int e = row_ptr[n], end = row_ptr[n + 1];
    while (e < end && (e & 3)) {
        int s = csr_src[e];
        uint2 hv = *reinterpret_cast<const uint2*>(h + (size_t)s * HD + c0);
        addpk(a0, a1, hv.x);
        addpk(a2, a3, hv.y);
        ++e;
    }
    for (; e + 15 < end; e += 16) {
        int4_v s0 = __builtin_nontemporal_load(reinterpret_cast<const int4_v*>(csr_src + e));
        int4_v s1 = __builtin_nontemporal_load(reinterpret_cast<const int4_v*>(csr_src + e + 4));
        int4_v s2 = __builtin_nontemporal_load(reinterpret_cast<const int4_v*>(csr_src + e + 8));
        int4_v s3 = __builtin_nontemporal_load(reinterpret_cast<const int4_v*>(csr_src + e + 12));
        uint2 g0 = *reinterpret_cast<const uint2*>(h + (size_t)s0[0] * HD + c0);
        uint2 g1 = *reinterpret_cast<const uint2*>(h + (size_t)s0[1] * HD + c0);
        uint2 g2 = *reinterpret_cast<const uint2*>(h + (size_t)s0[2] * HD + c0);
        uint2 g3 = *reinterpret_cast<const uint2*>(h + (size_t)s0[3] * HD + c0);
        uint2 g4 = *reinterpret_cast<const uint2*>(h + (size_t)s1[0] * HD + c0);
        uint2 g5 = *reinterpret_cast<const uint2*>(h + (size_t)s1[1] * HD + c0);
        uint2 g6 = *reinterpret_cast<const uint2*>(h + (size_t)s1[2] * HD + c0);
        uint2 g7 = *reinterpret_cast<const uint2*>(h + (size_t)s1[3] * HD + c0);
        uint2 g8 = *reinterpret_cast<const uint2*>(h + (size_t)s2[0] * HD + c0);
        uint2 g9 = *reinterpret_cast<const uint2*>(h + (size_t)s2[1] * HD + c0);
        uint2 ga = *reinterpret_cast<const uint2*>(h + (size_t)s2[2] * HD + c0);
        uint2 gb = *reinterpret_cast<const uint2*>(h + (size_t)s2[3] * HD + c0);
        uint2 gc = *reinterpret_cast<const uint2*>(h + (size_t)s3[0] * HD + c0);
        uint2 gd = *reinterpret_cast<const uint2*>(h + (size_t)s3[1] * HD + c0);
        uint2 ge = *reinterpret_cast<const uint2*>(h + (size_t)s3[2] * HD + c0);
        uint2 gf = *reinterpret_cast<const uint2*>(h + (size_t)s3[3] * HD + c0);
        addpk(a0, a1, g0.x); addpk(a2, a3, g0.y);
        addpk(a0, a1, g1.x); addpk(a2, a3, g1.y);
        addpk(a0, a1, g2.x); addpk(a2, a3, g2.y);
        addpk(a0, a1, g3.x); addpk(a2, a3, g3.y);
        addpk(a0, a1, g4.x); addpk(a2, a3, g4.y);
        addpk(a0, a1, g5.x); addpk(a2, a3, g5.y);
        addpk(a0, a1, g6.x); addpk(a2, a3, g6.y);
        addpk(a0, a1, g7.x); addpk(a2, a3, g7.y);
        addpk(a0, a1, g8.x); addpk(a2, a3, g8.y);
        addpk(a0, a1, g9.x); addpk(a2, a3, g9.y);
        addpk(a0, a1, ga.x); addpk(a2, a3, ga.y);
        addpk(a0, a1, gb.x); addpk(a2, a3, gb.y);
        addpk(a0, a1, gc.x); addpk(a2, a3, gc.y);
        addpk(a0, a1, gd.x); addpk(a2, a3, gd.y);
        addpk(a0, a1, ge.x); addpk(a2, a3, ge.y);
        addpk(a0, a1, gf.x); addpk(a2, a3, gf.y);
    }
    if (e + 7 < end) {
        int4 s0 = *reinterpret_cast<const int4*>(csr_src + e);
        int4 s1 = *reinterpret_cast<const int4*>(csr_src + e + 4);
        G4(s0);
        G4(s1);
        e += 8;
    }
    if (e + 3 < end) {
        int4 s0 = *reinterpret_cast<const int4*>(csr_src + e);
        G4(s0);
        e += 4;
    }
    for (; e < end; ++e) {
        int s = csr_src[e];
        uint2 hv = *reinterpret_cast<const uint2*>(h + (size_t)s * HD + c0);
        addpk(a0, a1, hv.x);
        addpk(a2, a3, hv.y);
    }

    float d = dis[n];
    float4 bv = *reinterpret_cast<const float4*>(bias + c0);
    float v0 = fmaxf(fmaf(a0, d, bv.x), 0.f);
    float v1 = fmaxf(fmaf(a1, d, bv.y), 0.f);
    float v2 = fmaxf(fmaf(a2, d, bv.z), 0.f);
    float v3 = fmaxf(fmaf(a3, d, bv.w), 0.f);

    if (DO_LN) {
        float s = (v0 + v1) + (v2 + v3);
        float s2 = (v0 * v0 + v1 * v1) + (v2 * v2 + v3 * v3);
#pragma unroll
        for (int m = 4; m >= 1; m >>= 1) {
            s += __shfl_xor(s, m, 8);
            s2 += __shfl_xor(s2, m, 8);
        }
        float mean = s * (1.f / 32.f);
        float var = s2 * (1.f / 32.f) - mean * mean;
        float r = rsqrtf(var + LN_EPS);
        float4 gv = *reinterpret_cast<const float4*>(g + c0);
        float4 lb = *reinterpret_cast<const float4*>(bln + c0);
        v0 = (v0 - mean) * r * gv.x + lb.x;
        v1 = (v1 - mean) * r * gv.y + lb.y;
        v2 = (v2 - mean) * r * gv.z + lb.z;
        v3 = (v3 - mean) * r * gv.w + lb.w;
    }
    float4_v ov;
    ov[0] = v0; ov[1] = v1; ov[2] = v2; ov[3] = v3;
    __builtin_nontemporal_store(ov, reinterpret_cast<float4_v*>(out + (size_t)n * HD + c0));
}

// ---------------- final: MLP head + log_softmax ----------------

__global__ void k_final(const float* __restrict__ hin,
                        const float* __restrict__ w1, const float* __restrict__ mb1,
                        const float* __restrict__ w2, const float* __restrict__ mb2,
                        float* __restrict__ out) {
    __shared__ float sw1[HD * MID], sw2[MID * OUTD], sb1[MID], sb2[OUTD];
    for (int t = threadIdx.x; t < HD * MID; t += blockDim.x) sw1[t] = w1[t];
    for (int t = threadIdx.x; t < MID * OUTD; t += blockDim.x) sw2[t] = w2[t];
    if (threadIdx.x < MID) sb1[threadIdx.x] = mb1[threadIdx.x];
    if (threadIdx.x < OUTD) sb2[threadIdx.x] = mb2[threadIdx.x];
    __syncthreads();
    int n = blockIdx.x * blockDim.x + threadIdx.x;
    if (n >= NN) return;
    float h[HD];
    const float* ar = hin + (size_t)n * HD;
#pragma unroll
    for (int k = 0; k < HD; ++k) h[k] = ar[k];
    float t[MID];
#pragma unroll
    for (int j = 0; j < MID; ++j) {
        float a = sb1[j];
#pragma unroll
        for (int k = 0; k < HD; ++k) a += h[k] * sw1[k * MID + j];
        t[j] = fmaxf(a, 0.f);
    }
    float o[OUTD];
#pragma unroll
    for (int j = 0; j < OUTD; ++j) {
        float a = sb2[j];
#pragma unroll
        for (int k = 0; k < MID; ++k) a += t[k] * sw2[k * OUTD + j];
        o[j] = a;
    }
    float mx = o[0];
#pragma unroll
    for (int j = 1; j < OUTD; ++j) mx = fmaxf(mx, o[j]);
    float se = 0.f;
#pragma unroll
    for (int j = 0; j < OUTD; ++j) se += __expf(o[j] - mx);
    float lse = __logf(se) + mx;
    float* orow = out + (size_t)n * OUTD;
#pragma unroll
    for (int j = 0; j < OUTD; ++j) orow[j] = o[j] - lse;
}

// ---------------- launch ----------------

extern "C" void kernel_launch(void* const* d_in, const int* in_sizes, int n_in,
                              void* d_out, int out_size, void* d_ws, size_t ws_size,
                              hipStream_t stream) {
    const float* x     = (const float*)d_in[0];
    const int*   ei    = (const int*)d_in[1];
    const float* W0    = (const float*)d_in[2];
    const float* b0    = (const float*)d_in[3];
    const float* W1    = (const float*)d_in[4];
    const float* b1    = (const float*)d_in[5];
    const float* W2    = (const float*)d_in[6];
    const float* b2    = (const float*)d_in[7];
    const float* ln0_g = (const float*)d_in[8];
    const float* ln0_b = (const float*)d_in[9];
    const float* ln1_g = (const float*)d_in[10];
    const float* ln1_b = (const float*)d_in[11];
    const float* mp_w1 = (const float*)d_in[12];
    const float* mp_b1 = (const float*)d_in[13];
    const float* mp_w2 = (const float*)d_in[14];
    const float* mp_b2 = (const float*)d_in[15];
    float* out = (float*)d_out;

    const int* src = ei;        // edge_index[0]
    const int* dst = ei + NE;   // edge_index[1]

    char* w = (char*)d_ws;
    auto align256 = [](size_t v) { return (v + 255) & ~(size_t)255; };
    int* g_bincur  = (int*)w;   w += align256((size_t)NB * 4);
    int* g_binexcl = (int*)w;   w += align256((size_t)NB * 4);
    int* row_ptr   = (int*)w;   w += align256((size_t)(NN + 1) * 4);
    float* dis     = (float*)w; w += align256((size_t)NN * 4);
    char* uni = w;              // union region (staging vs activations)
    unsigned short* bufB = (unsigned short*)uni;                  // bf16 hs, 6.4 MB
    float* bufA = (float*)(uni + align256((size_t)NN * HD * 2));  // f32 acts, 12.8 MB
    unsigned int* staged = (unsigned int*)uni;                    // NB*CAP*4 = 16.0 MB
    size_t uni_sz = align256((size_t)NB * CAP * 4);
    size_t uni_sz2 = align256((size_t)NN * HD * 2) + align256((size_t)NN * HD * 4);
    w = uni + (uni_sz > uni_sz2 ? uni_sz : uni_sz2);
    int* csr_src = (int*)w;

    const int BS = 256;
    int gN  = (NN + BS - 1) / BS;           // 391
    int gA  = (NE + EPB - 1) / EPB;         // 391
    int gN8 = (NN * 8 + BS - 1) / BS;       // 3125
    int gG  = (NN + 63) / 64;               // 1563

    // CSR build (binned counting sort)
    k_zero_bins<<<1, 512, 0, stream>>>(g_bincur);
    k_binA<<<gA, ABS, 0, stream>>>(src, dst, g_bincur, staged);
    k_binscan<<<1, 512, 0, stream>>>(g_bincur, g_binexcl, row_ptr);
    k_binC<<<NB, CBS, 0, stream>>>(g_bincur, g_binexcl, staged, row_ptr, dis, csr_src);

    // layer 0
    k_gemm<DIN><<<gG, BS, 0, stream>>>(x, W0, dis, bufB);
    k_gather<1><<<gN8, BS, 0, stream>>>(row_ptr, csr_src, dis, bufB, b0,
                                        ln0_g, ln0_b, bufA);
    // layer 1
    k_gemm<HD><<<gG, BS, 0, stream>>>(bufA, W1, dis, bufB);
    k_gather<1><<<gN8, BS, 0, stream>>>(row_ptr, csr_src, dis, bufB, b1,
                                        ln1_g, ln1_b, bufA);
    // layer 2 (no LN)
    k_gemm<HD><<<gG, BS, 0, stream>>>(bufA, W2, dis, bufB);
    k_gather<0><<<gN8, BS, 0, stream>>>(row_ptr, csr_src, dis, bufB, b2,
                                        nullptr, nullptr, bufA);

    // head
    k_final<<<gN, BS, 0, stream>>>(bufA, mp_w1, mp_b1, mp_w2, mp_b2, out);
}

// Round 14
// 256.798 us; speedup vs baseline: 1.3293x; 1.3293x over previous
//
#include <hip/hip_runtime.h>

#define NN 100000
#define NE 3200000
#define DIN 128
#define HD 32
#define MID 16
#define OUTD 8
#define LN_EPS 1e-5f

#define BINSHIFT 8                 // 256 nodes per bin
#define NB 391                     // ceil(NN / 256)
#define CAP 10240                  // bin capacity (mean 8192)
#define EPB 8192                   // edges per pass-A block
#define ABS 1024                   // pass-A block size (16 waves/block)
#define AITER (EPB / ABS)          // 8
#define CBS 1024                   // pass-C block size

// true clang vector type (required by __builtin_nontemporal_*)
typedef float float4_v __attribute__((ext_vector_type(4)));

// ---------------- bf16 helpers ----------------

__device__ __forceinline__ float bf2f(unsigned short u) {
    union { unsigned int i; float f; } c;
    c.i = ((unsigned int)u) << 16;
    return c.f;
}
__device__ __forceinline__ unsigned short f2bf(float f) {
    union { float f; unsigned int i; } c;
    c.f = f;
    unsigned int r = c.i + 0x7FFFu + ((c.i >> 16) & 1u);  // RNE
    return (unsigned short)(r >> 16);
}
__device__ __forceinline__ unsigned int pack2(float a, float b) {
    return (unsigned int)f2bf(a) | ((unsigned int)f2bf(b) << 16);
}
__device__ __forceinline__ void addpk(float& a0, float& a1, unsigned int u) {
    union { unsigned int i; float f; } lo, hi;
    lo.i = u << 16;
    hi.i = u & 0xFFFF0000u;
    a0 += lo.f;
    a1 += hi.f;
}

// ---------------- binned CSR build ----------------

__global__ void k_zero_bins(int* __restrict__ g_bincur) {
    int i = blockIdx.x * blockDim.x + threadIdx.x;
    if (i < NB) g_bincur[i] = 0;
}

// Pass A with LDS regroup: histogram -> scan -> pack edges bin-contiguously in
// LDS -> coalesced run writes to global staging.
__global__ __launch_bounds__(ABS) void k_binA(const int* __restrict__ src,
                                              const int* __restrict__ dst,
                                              int* __restrict__ g_bincur,
                                              unsigned int* __restrict__ staged) {
    __shared__ int cnt[512];              // histogram -> cursor
    __shared__ int obin[512];             // intra-block exclusive offsets
    __shared__ int base[NB];              // global reserved base per bin
    __shared__ unsigned short sbin[EPB];  // slot -> bin
    __shared__ unsigned int sedge[EPB];   // packed edges, bin-grouped
    int tid = threadIdx.x;
    if (tid < 512) cnt[tid] = 0;
    __syncthreads();
    int e0 = blockIdx.x * EPB;
    int total = min(EPB, NE - e0);
    int dreg[AITER];
#pragma unroll
    for (int i = 0; i < AITER; ++i) {
        int e = e0 + i * ABS + tid;
        dreg[i] = (e < NE) ? dst[e] : -1;
        if (dreg[i] >= 0) atomicAdd(&cnt[dreg[i] >> BINSHIFT], 1);
    }
    __syncthreads();
    // exclusive scan over 512 bins
    int v = 0;
    if (tid < 512) {
        v = cnt[tid];
        obin[tid] = v;
    }
    __syncthreads();
#pragma unroll
    for (int off = 1; off < 512; off <<= 1) {
        int t = (tid < 512 && tid >= off) ? obin[tid - off] : 0;
        __syncthreads();
        if (tid < 512) obin[tid] += t;
        __syncthreads();
    }
    if (tid < 512) obin[tid] -= v;  // exclusive
    __syncthreads();
    // reserve global space, fill slot->bin map, reset cursors
    if (tid < NB) {
        int c = cnt[tid];
        base[tid] = c ? atomicAdd(&g_bincur[tid], c) : 0;
        int s0 = obin[tid];
        for (int k = 0; k < c; ++k) sbin[s0 + k] = (unsigned short)tid;
    }
    if (tid < 512) cnt[tid] = 0;
    __syncthreads();
    // place edges into LDS grouped by bin
#pragma unroll
    for (int i = 0; i < AITER; ++i) {
        int e = e0 + i * ABS + tid;
        int d = dreg[i];
        if (d >= 0) {
            int b = d >> BINSHIFT;
            int slot = obin[b] + atomicAdd(&cnt[b], 1);
            sedge[slot] = ((unsigned int)(d & 255) << 24) | (unsigned int)src[e];
        }
    }
    __syncthreads();
    // coalesced write-out: consecutive threads -> consecutive slots
#pragma unroll
    for (int i = 0; i < AITER; ++i) {
        int s = i * ABS + tid;
        if (s < total) {
            int b = sbin[s];
            int k = base[b] + (s - obin[b]);
            if (k < CAP) staged[(size_t)b * CAP + k] = sedge[s];
        }
    }
}

__global__ void k_binscan(const int* __restrict__ g_bincur, int* __restrict__ g_binexcl,
                          int* __restrict__ row_ptr) {
    __shared__ int s[512];
    int v = (threadIdx.x < NB) ? min(g_bincur[threadIdx.x], CAP) : 0;
    s[threadIdx.x] = v;
    __syncthreads();
#pragma unroll
    for (int off = 1; off < 512; off <<= 1) {
        int t = (threadIdx.x >= off) ? s[threadIdx.x - off] : 0;
        __syncthreads();
        s[threadIdx.x] += t;
        __syncthreads();
    }
    if (threadIdx.x < NB) g_binexcl[threadIdx.x] = s[threadIdx.x] - v;
    if (threadIdx.x == NB - 1) row_ptr[NN] = s[threadIdx.x];
}

__global__ __launch_bounds__(CBS) void k_binC(const int* __restrict__ g_bincur,
                                              const int* __restrict__ g_binexcl,
                                              const unsigned int* __restrict__ staged,
                                              int* __restrict__ row_ptr,
                                              float* __restrict__ dis,
                                              int* __restrict__ csr_src) {
    __shared__ int cnt[256];
    __shared__ int scn[256];
    int b = blockIdx.x;
    int tid = threadIdx.x;
    int tot = min(g_bincur[b], CAP);
    if (tid < 256) cnt[tid] = 0;
    __syncthreads();
    const unsigned int* st = staged + (size_t)b * CAP;
    for (int i = tid; i < tot; i += CBS)
        atomicAdd(&cnt[st[i] >> 24], 1);
    __syncthreads();
    int v = 0;
    if (tid < 256) {
        v = cnt[tid];
        scn[tid] = v;
    }
    __syncthreads();
#pragma unroll
    for (int off = 1; off < 256; off <<= 1) {
        int t = (tid < 256 && tid >= off) ? scn[tid - off] : 0;
        __syncthreads();
        if (tid < 256) scn[tid] += t;
        __syncthreads();
    }
    int gbase = g_binexcl[b];
    if (tid < 256) {
        int excl = scn[tid] - v;
        int node = (b << BINSHIFT) + tid;
        if (node < NN) {
            row_ptr[node] = gbase + excl;
            dis[node] = rsqrtf((float)(v + 1));  // +1 self-loop
        }
        cnt[tid] = excl;  // reuse as scatter cursor
    }
    __syncthreads();
    for (int i = tid; i < tot; i += CBS) {
        unsigned int p = st[i];
        int rank = atomicAdd(&cnt[p >> 24], 1);
        csr_src[gbase + rank] = (int)(p & 0xFFFFFFu);
    }
}

// ---------------- GEMM: block = 64 nodes x 4 waves; W staged in LDS ----------------

template <int K>
__global__ __launch_bounds__(256) void k_gemm(const float* __restrict__ x,
                                              const float* __restrict__ W,
                                              const float* __restrict__ dis,
                                              unsigned short* __restrict__ hs) {
    __shared__ float sW[K * HD];
    for (int t = threadIdx.x; t < K * HD; t += 256) sW[t] = W[t];
    __syncthreads();
    int lane = threadIdx.x & 63;
    int q = __builtin_amdgcn_readfirstlane(threadIdx.x >> 6);  // 0..3, SGPR
    int n = blockIdx.x * 64 + lane;
    if (n >= NN) return;
    const float* xr = x + (size_t)n * K;
    const float* Wq = sW + q * 8;
    float acc[8];
#pragma unroll
    for (int j = 0; j < 8; ++j) acc[j] = 0.f;
    for (int k0 = 0; k0 < K; k0 += 4) {
        float4 xv = *reinterpret_cast<const float4*>(xr + k0);  // cached load
#pragma unroll
        for (int kk = 0; kk < 4; ++kk) {
            float xk = kk == 0 ? xv.x : kk == 1 ? xv.y : kk == 2 ? xv.z : xv.w;
#pragma unroll
            for (int j = 0; j < 8; ++j)
                acc[j] = fmaf(xk, Wq[(k0 + kk) * HD + j], acc[j]);
        }
    }
    float d = dis[n];
    uint4 p;
    p.x = pack2(acc[0] * d, acc[1] * d);
    p.y = pack2(acc[2] * d, acc[3] * d);
    p.z = pack2(acc[4] * d, acc[5] * d);
    p.w = pack2(acc[6] * d, acc[7] * d);
    *reinterpret_cast<uint4*>(hs + (size_t)n * HD + q * 8) = p;
}

// ---------------- gather: 8 lanes/node, 4 ch/lane ----------------

#define G4(si) \
    { \
        uint2 g0 = *reinterpret_cast<const uint2*>(h + (size_t)(si).x * HD + c0); \
        uint2 g1 = *reinterpret_cast<const uint2*>(h + (size_t)(si).y * HD + c0); \
        uint2 g2 = *reinterpret_cast<const uint2*>(h + (size_t)(si).z * HD + c0); \
        uint2 g3 = *reinterpret_cast<const uint2*>(h + (size_t)(si).w * HD + c0); \
        addpk(a0, a1, g0.x); addpk(a2, a3, g0.y); \
        addpk(a0, a1, g1.x); addpk(a2, a3, g1.y); \
        addpk(a0, a1, g2.x); addpk(a2, a3, g2.y); \
        addpk(a0, a1, g3.x); addpk(a2, a3, g3.y); \
    }

template <int DO_LN>
__global__ __launch_bounds__(256) void k_gather(
        const int* __restrict__ row_ptr, const int* __restrict__ csr_src,
        const float* __restrict__ dis, const unsigned short* __restrict__ h,
        const float* __restrict__ bias, const float* __restrict__ g,
        const float* __restrict__ bln, float* __restrict__ out) {
    int idx = blockIdx.x * blockDim.x + threadIdx.x;
    int n = idx >> 3, sub = idx & 7;
    if (n >= NN) return;
    int c0 = sub << 2;

    uint2 u = *reinterpret_cast<const uint2*>(h + (size_t)n * HD + c0);  // self-loop
    float a0 = 0.f, a1 = 0.f, a2 = 0.f, a3 = 0.f;
    addpk(a0, a1, u.x);
    addpk(a2, a3, u.y);

    int e = row_ptr[n], end = row_ptr[n + 1];
    while (e < end && (e & 3)) {
        int s = csr_src[e];
        uint2 hv = *reinterpret_cast<const uint2*>(h + (size_t)s * HD + c0);
        addpk(a0, a1, hv.x);
        addpk(a2, a3, hv.y);
        ++e;
    }
    for (; e + 15 < end; e += 16) {
        int4 s0 = *reinterpret_cast<const int4*>(csr_src + e);
        int4 s1 = *reinterpret_cast<const int4*>(csr_src + e + 4);
        int4 s2 = *reinterpret_cast<const int4*>(csr_src + e + 8);
        int4 s3 = *reinterpret_cast<const int4*>(csr_src + e + 12);
        uint2 g0 = *reinterpret_cast<const uint2*>(h + (size_t)s0.x * HD + c0);
        uint2 g1 = *reinterpret_cast<const uint2*>(h + (size_t)s0.y * HD + c0);
        uint2 g2 = *reinterpret_cast<const uint2*>(h + (size_t)s0.z * HD + c0);
        uint2 g3 = *reinterpret_cast<const uint2*>(h + (size_t)s0.w * HD + c0);
        uint2 g4 = *reinterpret_cast<const uint2*>(h + (size_t)s1.x * HD + c0);
        uint2 g5 = *reinterpret_cast<const uint2*>(h + (size_t)s1.y * HD + c0);
        uint2 g6 = *reinterpret_cast<const uint2*>(h + (size_t)s1.z * HD + c0);
        uint2 g7 = *reinterpret_cast<const uint2*>(h + (size_t)s1.w * HD + c0);
        uint2 g8 = *reinterpret_cast<const uint2*>(h + (size_t)s2.x * HD + c0);
        uint2 g9 = *reinterpret_cast<const uint2*>(h + (size_t)s2.y * HD + c0);
        uint2 ga = *reinterpret_cast<const uint2*>(h + (size_t)s2.z * HD + c0);
        uint2 gb = *reinterpret_cast<const uint2*>(h + (size_t)s2.w * HD + c0);
        uint2 gc = *reinterpret_cast<const uint2*>(h + (size_t)s3.x * HD + c0);
        uint2 gd = *reinterpret_cast<const uint2*>(h + (size_t)s3.y * HD + c0);
        uint2 ge = *reinterpret_cast<const uint2*>(h + (size_t)s3.z * HD + c0);
        uint2 gf = *reinterpret_cast<const uint2*>(h + (size_t)s3.w * HD + c0);
        addpk(a0, a1, g0.x); addpk(a2, a3, g0.y);
        addpk(a0, a1, g1.x); addpk(a2, a3, g1.y);
        addpk(a0, a1, g2.x); addpk(a2, a3, g2.y);
        addpk(a0, a1, g3.x); addpk(a2, a3, g3.y);
        addpk(a0, a1, g4.x); addpk(a2, a3, g4.y);
        addpk(a0, a1, g5.x); addpk(a2, a3, g5.y);
        addpk(a0, a1, g6.x); addpk(a2, a3, g6.y);
        addpk(a0, a1, g7.x); addpk(a2, a3, g7.y);
        addpk(a0, a1, g8.x); addpk(a2, a3, g8.y);
        addpk(a0, a1, g9.x); addpk(a2, a3, g9.y);
        addpk(a0, a1, ga.x); addpk(a2, a3, ga.y);
        addpk(a0, a1, gb.x); addpk(a2, a3, gb.y);
        addpk(a0, a1, gc.x); addpk(a2, a3, gc.y);
        addpk(a0, a1, gd.x); addpk(a2, a3, gd.y);
        addpk(a0, a1, ge.x); addpk(a2, a3, ge.y);
        addpk(a0, a1, gf.x); addpk(a2, a3, gf.y);
    }
    if (e + 7 < end) {
        int4 s0 = *reinterpret_cast<const int4*>(csr_src + e);
        int4 s1 = *reinterpret_cast<const int4*>(csr_src + e + 4);
        G4(s0);
        G4(s1);
        e += 8;
    }
    if (e + 3 < end) {
        int4 s0 = *reinterpret_cast<const int4*>(csr_src + e);
        G4(s0);
        e += 4;
    }
    for (; e < end; ++e) {
        int s = csr_src[e];
        uint2 hv = *reinterpret_cast<const uint2*>(h + (size_t)s * HD + c0);
        addpk(a0, a1, hv.x);
        addpk(a2, a3, hv.y);
    }

    float d = dis[n];
    float4 bv = *reinterpret_cast<const float4*>(bias + c0);
    float v0 = fmaxf(fmaf(a0, d, bv.x), 0.f);
    float v1 = fmaxf(fmaf(a1, d, bv.y), 0.f);
    float v2 = fmaxf(fmaf(a2, d, bv.z), 0.f);
    float v3 = fmaxf(fmaf(a3, d, bv.w), 0.f);

    if (DO_LN) {
        float s = (v0 + v1) + (v2 + v3);
        float s2 = (v0 * v0 + v1 * v1) + (v2 * v2 + v3 * v3);
#pragma unroll
        for (int m = 4; m >= 1; m >>= 1) {
            s += __shfl_xor(s, m, 8);
            s2 += __shfl_xor(s2, m, 8);
        }
        float mean = s * (1.f / 32.f);
        float var = s2 * (1.f / 32.f) - mean * mean;
        float r = rsqrtf(var + LN_EPS);
        float4 gv = *reinterpret_cast<const float4*>(g + c0);
        float4 lb = *reinterpret_cast<const float4*>(bln + c0);
        v0 = (v0 - mean) * r * gv.x + lb.x;
        v1 = (v1 - mean) * r * gv.y + lb.y;
        v2 = (v2 - mean) * r * gv.z + lb.z;
        v3 = (v3 - mean) * r * gv.w + lb.w;
    }
    // full-line write-once stream: nt store is safe (frees L2 for h-table)
    float4_v ov;
    ov[0] = v0; ov[1] = v1; ov[2] = v2; ov[3] = v3;
    __builtin_nontemporal_store(ov, reinterpret_cast<float4_v*>(out + (size_t)n * HD + c0));
}

// ---------------- final: MLP head + log_softmax ----------------

__global__ void k_final(const float* __restrict__ hin,
                        const float* __restrict__ w1, const float* __restrict__ mb1,
                        const float* __restrict__ w2, const float* __restrict__ mb2,
                        float* __restrict__ out) {
    __shared__ float sw1[HD * MID], sw2[MID * OUTD], sb1[MID], sb2[OUTD];
    for (int t = threadIdx.x; t < HD * MID; t += blockDim.x) sw1[t] = w1[t];
    for (int t = threadIdx.x; t < MID * OUTD; t += blockDim.x) sw2[t] = w2[t];
    if (threadIdx.x < MID) sb1[threadIdx.x] = mb1[threadIdx.x];
    if (threadIdx.x < OUTD) sb2[threadIdx.x] = mb2[threadIdx.x];
    __syncthreads();
    int n = blockIdx.x * blockDim.x + threadIdx.x;
    if (n >= NN) return;
    float h[HD];
    const float* ar = hin + (size_t)n * HD;
#pragma unroll
    for (int k = 0; k < HD; ++k) h[k] = ar[k];
    float t[MID];
#pragma unroll
    for (int j = 0; j < MID; ++j) {
        float a = sb1[j];
#pragma unroll
        for (int k = 0; k < HD; ++k) a += h[k] * sw1[k * MID + j];
        t[j] = fmaxf(a, 0.f);
    }
    float o[OUTD];
#pragma unroll
    for (int j = 0; j < OUTD; ++j) {
        float a = sb2[j];
#pragma unroll
        for (int k = 0; k < MID; ++k) a += t[k] * sw2[k * OUTD + j];
        o[j] = a;
    }
    float mx = o[0];
#pragma unroll
    for (int j = 1; j < OUTD; ++j) mx = fmaxf(mx, o[j]);
    float se = 0.f;
#pragma unroll
    for (int j = 0; j < OUTD; ++j) se += __expf(o[j] - mx);
    float lse = __logf(se) + mx;
    float* orow = out + (size_t)n * OUTD;
#pragma unroll
    for (int j = 0; j < OUTD; ++j) orow[j] = o[j] - lse;
}

// ---------------- launch ----------------

extern "C" void kernel_launch(void* const* d_in, const int* in_sizes, int n_in,
                              void* d_out, int out_size, void* d_ws, size_t ws_size,
                              hipStream_t stream) {
    const float* x     = (const float*)d_in[0];
    const int*   ei    = (const int*)d_in[1];
    const float* W0    = (const float*)d_in[2];
    const float* b0    = (const float*)d_in[3];
    const float* W1    = (const float*)d_in[4];
    const float* b1    = (const float*)d_in[5];
    const float* W2    = (const float*)d_in[6];
    const float* b2    = (const float*)d_in[7];
    const float* ln0_g = (const float*)d_in[8];
    const float* ln0_b = (const float*)d_in[9];
    const float* ln1_g = (const float*)d_in[10];
    const float* ln1_b = (const float*)d_in[11];
    const float* mp_w1 = (const float*)d_in[12];
    const float* mp_b1 = (const float*)d_in[13];
    const float* mp_w2 = (const float*)d_in[14];
    const float* mp_b2 = (const float*)d_in[15];
    float* out = (float*)d_out;

    const int* src = ei;        // edge_index[0]
    const int* dst = ei + NE;   // edge_index[1]

    char* w = (char*)d_ws;
    auto align256 = [](size_t v) { return (v + 255) & ~(size_t)255; };
    int* g_bincur  = (int*)w;   w += align256((size_t)NB * 4);
    int* g_binexcl = (int*)w;   w += align256((size_t)NB * 4);
    int* row_ptr   = (int*)w;   w += align256((size_t)(NN + 1) * 4);
    float* dis     = (float*)w; w += align256((size_t)NN * 4);
    char* uni = w;              // union region (staging vs activations)
    unsigned short* bufB = (unsigned short*)uni;                  // bf16 hs, 6.4 MB
    float* bufA = (float*)(uni + align256((size_t)NN * HD * 2));  // f32 acts, 12.8 MB
    unsigned int* staged = (unsigned int*)uni;                    // NB*CAP*4 = 16.0 MB
    size_t uni_sz = align256((size_t)NB * CAP * 4);
    size_t uni_sz2 = align256((size_t)NN * HD * 2) + align256((size_t)NN * HD * 4);
    w = uni + (uni_sz > uni_sz2 ? uni_sz : uni_sz2);
    int* csr_src = (int*)w;

    const int BS = 256;
    int gN  = (NN + BS - 1) / BS;           // 391
    int gA  = (NE + EPB - 1) / EPB;         // 391
    int gN8 = (NN * 8 + BS - 1) / BS;       // 3125
    int gG  = (NN + 63) / 64;               // 1563

    // CSR build (binned counting sort)
    k_zero_bins<<<1, 512, 0, stream>>>(g_bincur);
    k_binA<<<gA, ABS, 0, stream>>>(src, dst, g_bincur, staged);
    k_binscan<<<1, 512, 0, stream>>>(g_bincur, g_binexcl, row_ptr);
    k_binC<<<NB, CBS, 0, stream>>>(g_bincur, g_binexcl, staged, row_ptr, dis, csr_src);

    // layer 0
    k_gemm<DIN><<<gG, BS, 0, stream>>>(x, W0, dis, bufB);
    k_gather<1><<<gN8, BS, 0, stream>>>(row_ptr, csr_src, dis, bufB, b0,
                                        ln0_g, ln0_b, bufA);
    // layer 1
    k_gemm<HD><<<gG, BS, 0, stream>>>(bufA, W1, dis, bufB);
    k_gather<1><<<gN8, BS, 0, stream>>>(row_ptr, csr_src, dis, bufB, b1,
                                        ln1_g, ln1_b, bufA);
    // layer 2 (no LN)
    k_gemm<HD><<<gG, BS, 0, stream>>>(bufA, W2, dis, bufB);
    k_gather<0><<<gN8, BS, 0, stream>>>(row_ptr, csr_src, dis, bufB, b2,
                                        nullptr, nullptr, bufA);

    // head
    k_final<<<gN, BS, 0, stream>>>(bufA, mp_w1, mp_b1, mp_w2, mp_b2, out);
}

// Round 15
// 237.815 us; speedup vs baseline: 1.4355x; 1.0798x over previous
//
#include <hip/hip_runtime.h>

#define NN 100000
#define NE 3200000
#define DIN 128
#define HD 32
#define MID 16
#define OUTD 8
#define LN_EPS 1e-5f

#define BINSHIFT 8                 // 256 nodes per bin
#define NB 391                     // ceil(NN / 256)
#define CAP 10240                  // bin capacity (mean 8192)
#define EPB 8192                   // edges per pass-A block
#define ABS 1024                   // pass-A block size (16 waves/block)
#define AITER (EPB / ABS)          // 8
#define CBS 1024                   // pass-C block size

// true clang vector types
typedef float float4_v __attribute__((ext_vector_type(4)));
typedef short short8   __attribute__((ext_vector_type(8)));
typedef float f32x4    __attribute__((ext_vector_type(4)));

// ---------------- bf16 helpers ----------------

__device__ __forceinline__ float bf2f(unsigned short u) {
    union { unsigned int i; float f; } c;
    c.i = ((unsigned int)u) << 16;
    return c.f;
}
__device__ __forceinline__ unsigned short f2bf(float f) {
    union { float f; unsigned int i; } c;
    c.f = f;
    unsigned int r = c.i + 0x7FFFu + ((c.i >> 16) & 1u);  // RNE
    return (unsigned short)(r >> 16);
}
__device__ __forceinline__ unsigned int pack2(float a, float b) {
    return (unsigned int)f2bf(a) | ((unsigned int)f2bf(b) << 16);
}
__device__ __forceinline__ void addpk(float& a0, float& a1, unsigned int u) {
    union { unsigned int i; float f; } lo, hi;
    lo.i = u << 16;
    hi.i = u & 0xFFFF0000u;
    a0 += lo.f;
    a1 += hi.f;
}

// ---------------- binned CSR build ----------------

__global__ void k_zero_bins(int* __restrict__ g_bincur) {
    int i = blockIdx.x * blockDim.x + threadIdx.x;
    if (i < NB) g_bincur[i] = 0;
}

__global__ __launch_bounds__(ABS) void k_binA(const int* __restrict__ src,
                                              const int* __restrict__ dst,
                                              int* __restrict__ g_bincur,
                                              unsigned int* __restrict__ staged) {
    __shared__ int cnt[512];              // histogram -> cursor
    __shared__ int obin[512];             // intra-block exclusive offsets
    __shared__ int base[NB];              // global reserved base per bin
    __shared__ unsigned short sbin[EPB];  // slot -> bin
    __shared__ unsigned int sedge[EPB];   // packed edges, bin-grouped
    int tid = threadIdx.x;
    if (tid < 512) cnt[tid] = 0;
    __syncthreads();
    int e0 = blockIdx.x * EPB;
    int total = min(EPB, NE - e0);
    int dreg[AITER];
#pragma unroll
    for (int i = 0; i < AITER; ++i) {
        int e = e0 + i * ABS + tid;
        dreg[i] = (e < NE) ? dst[e] : -1;
        if (dreg[i] >= 0) atomicAdd(&cnt[dreg[i] >> BINSHIFT], 1);
    }
    __syncthreads();
    int v = 0;
    if (tid < 512) {
        v = cnt[tid];
        obin[tid] = v;
    }
    __syncthreads();
#pragma unroll
    for (int off = 1; off < 512; off <<= 1) {
        int t = (tid < 512 && tid >= off) ? obin[tid - off] : 0;
        __syncthreads();
        if (tid < 512) obin[tid] += t;
        __syncthreads();
    }
    if (tid < 512) obin[tid] -= v;  // exclusive
    __syncthreads();
    if (tid < NB) {
        int c = cnt[tid];
        base[tid] = c ? atomicAdd(&g_bincur[tid], c) : 0;
        int s0 = obin[tid];
        for (int k = 0; k < c; ++k) sbin[s0 + k] = (unsigned short)tid;
    }
    if (tid < 512) cnt[tid] = 0;
    __syncthreads();
#pragma unroll
    for (int i = 0; i < AITER; ++i) {
        int e = e0 + i * ABS + tid;
        int d = dreg[i];
        if (d >= 0) {
            int b = d >> BINSHIFT;
            int slot = obin[b] + atomicAdd(&cnt[b], 1);
            sedge[slot] = ((unsigned int)(d & 255) << 24) | (unsigned int)src[e];
        }
    }
    __syncthreads();
#pragma unroll
    for (int i = 0; i < AITER; ++i) {
        int s = i * ABS + tid;
        if (s < total) {
            int b = sbin[s];
            int k = base[b] + (s - obin[b]);
            if (k < CAP) staged[(size_t)b * CAP + k] = sedge[s];
        }
    }
}

__global__ void k_binscan(const int* __restrict__ g_bincur, int* __restrict__ g_binexcl,
                          int* __restrict__ row_ptr) {
    __shared__ int s[512];
    int v = (threadIdx.x < NB) ? min(g_bincur[threadIdx.x], CAP) : 0;
    s[threadIdx.x] = v;
    __syncthreads();
#pragma unroll
    for (int off = 1; off < 512; off <<= 1) {
        int t = (threadIdx.x >= off) ? s[threadIdx.x - off] : 0;
        __syncthreads();
        s[threadIdx.x] += t;
        __syncthreads();
    }
    if (threadIdx.x < NB) g_binexcl[threadIdx.x] = s[threadIdx.x] - v;
    if (threadIdx.x == NB - 1) row_ptr[NN] = s[threadIdx.x];
}

__global__ __launch_bounds__(CBS) void k_binC(const int* __restrict__ g_bincur,
                                              const int* __restrict__ g_binexcl,
                                              const unsigned int* __restrict__ staged,
                                              int* __restrict__ row_ptr,
                                              float* __restrict__ dis,
                                              int* __restrict__ csr_src) {
    __shared__ int cnt[256];
    __shared__ int scn[256];
    int b = blockIdx.x;
    int tid = threadIdx.x;
    int tot = min(g_bincur[b], CAP);
    if (tid < 256) cnt[tid] = 0;
    __syncthreads();
    const unsigned int* st = staged + (size_t)b * CAP;
    for (int i = tid; i < tot; i += CBS)
        atomicAdd(&cnt[st[i] >> 24], 1);
    __syncthreads();
    int v = 0;
    if (tid < 256) {
        v = cnt[tid];
        scn[tid] = v;
    }
    __syncthreads();
#pragma unroll
    for (int off = 1; off < 256; off <<= 1) {
        int t = (tid < 256 && tid >= off) ? scn[tid - off] : 0;
        __syncthreads();
        if (tid < 256) scn[tid] += t;
        __syncthreads();
    }
    int gbase = g_binexcl[b];
    if (tid < 256) {
        int excl = scn[tid] - v;
        int node = (b << BINSHIFT) + tid;
        if (node < NN) {
            row_ptr[node] = gbase + excl;
            dis[node] = rsqrtf((float)(v + 1));  // +1 self-loop
        }
        cnt[tid] = excl;  // reuse as scatter cursor
    }
    __syncthreads();
    for (int i = tid; i < tot; i += CBS) {
        unsigned int p = st[i];
        int rank = atomicAdd(&cnt[p >> 24], 1);
        csr_src[gbase + rank] = (int)(p & 0xFFFFFFu);
    }
}

// ---------------- layer-0 GEMM via MFMA (x -> bf16 staged in LDS) ----------------
// Block = 64 nodes x 4 waves; wave computes 16 nodes x 32 outputs with
// 8x mfma_f32_16x16x32_bf16. All global reads fully coalesced.

template <int K>
__global__ __launch_bounds__(256) void k_gemm_mfma(const float* __restrict__ x,
                                                   const float* __restrict__ W,
                                                   const float* __restrict__ dis,
                                                   unsigned short* __restrict__ hs) {
    constexpr int XP = K + 8;  // padded row stride (bf16 units; 16B-aligned rows)
    __shared__ unsigned short xb[64 * XP];
    __shared__ unsigned short wt[HD * XP];   // W^T: [j][k]
    __shared__ float sdis[64];
    int tid = threadIdx.x;
    int n0 = blockIdx.x * 64;
    // stage W^T (coalesced; W stored [k][32])
    for (int f = tid; f < K * HD; f += 256) {
        int k = f >> 5, j = f & 31;
        wt[j * XP + k] = f2bf(W[f]);
    }
    if (tid < 64) {
        int nn = n0 + tid;
        sdis[tid] = dis[nn < NN ? nn : NN - 1];
    }
    // stage x tile bf16 (coalesced float4 loads)
    constexpr int FQ = K / 4;
    for (int f = tid; f < 64 * FQ; f += 256) {
        int node = f / FQ, kq = f % FQ;
        int nn = n0 + node;
        if (nn < NN) {
            float4 xv = *reinterpret_cast<const float4*>(x + (size_t)nn * K + kq * 4);
            unsigned short* p = &xb[node * XP + kq * 4];
            p[0] = f2bf(xv.x);
            p[1] = f2bf(xv.y);
            p[2] = f2bf(xv.z);
            p[3] = f2bf(xv.w);
        }
    }
    __syncthreads();
    int w = tid >> 6, l = tid & 63;
    int arow = l & 15, kg = l >> 4;  // A row / k-group per fragment layout
    f32x4 acc0 = {0.f, 0.f, 0.f, 0.f};
    f32x4 acc1 = {0.f, 0.f, 0.f, 0.f};
#pragma unroll
    for (int ks = 0; ks < K / 32; ++ks) {
        short8 a  = *reinterpret_cast<const short8*>(&xb[(w * 16 + arow) * XP + ks * 32 + kg * 8]);
        short8 b0 = *reinterpret_cast<const short8*>(&wt[arow * XP + ks * 32 + kg * 8]);
        short8 b1 = *reinterpret_cast<const short8*>(&wt[(16 + arow) * XP + ks * 32 + kg * 8]);
        acc0 = __builtin_amdgcn_mfma_f32_16x16x32_bf16(a, b0, acc0, 0, 0, 0);
        acc1 = __builtin_amdgcn_mfma_f32_16x16x32_bf16(a, b1, acc1, 0, 0, 0);
    }
    // D layout: col = lane&15 (output j), row = (lane>>4)*4 + r (node-in-16)
#pragma unroll
    for (int r = 0; r < 4; ++r) {
        int nloc = w * 16 + kg * 4 + r;
        int nn = n0 + nloc;
        if (nn < NN) {
            float d = sdis[nloc];
            hs[(size_t)nn * HD + arow]      = f2bf(acc0[r] * d);
            hs[(size_t)nn * HD + 16 + arow] = f2bf(acc1[r] * d);
        }
    }
}

// ---------------- GEMM (layers 1-2): block = 64 nodes x 4 waves; W in LDS ----------------

template <int K>
__global__ __launch_bounds__(256) void k_gemm(const float* __restrict__ x,
                                              const float* __restrict__ W,
                                              const float* __restrict__ dis,
                                              unsigned short* __restrict__ hs) {
    __shared__ float sW[K * HD];
    for (int t = threadIdx.x; t < K * HD; t += 256) sW[t] = W[t];
    __syncthreads();
    int lane = threadIdx.x & 63;
    int q = __builtin_amdgcn_readfirstlane(threadIdx.x >> 6);  // 0..3, SGPR
    int n = blockIdx.x * 64 + lane;
    if (n >= NN) return;
    const float* xr = x + (size_t)n * K;
    const float* Wq = sW + q * 8;
    float acc[8];
#pragma unroll
    for (int j = 0; j < 8; ++j) acc[j] = 0.f;
    for (int k0 = 0; k0 < K; k0 += 4) {
        float4 xv = *reinterpret_cast<const float4*>(xr + k0);
#pragma unroll
        for (int kk = 0; kk < 4; ++kk) {
            float xk = kk == 0 ? xv.x : kk == 1 ? xv.y : kk == 2 ? xv.z : xv.w;
#pragma unroll
            for (int j = 0; j < 8; ++j)
                acc[j] = fmaf(xk, Wq[(k0 + kk) * HD + j], acc[j]);
        }
    }
    float d = dis[n];
    uint4 p;
    p.x = pack2(acc[0] * d, acc[1] * d);
    p.y = pack2(acc[2] * d, acc[3] * d);
    p.z = pack2(acc[4] * d, acc[5] * d);
    p.w = pack2(acc[6] * d, acc[7] * d);
    *reinterpret_cast<uint4*>(hs + (size_t)n * HD + q * 8) = p;
}

// ---------------- gather: 8 lanes/node, 4 ch/lane ----------------

#define G4(si) \
    { \
        uint2 g0 = *reinterpret_cast<const uint2*>(h + (size_t)(si).x * HD + c0); \
        uint2 g1 = *reinterpret_cast<const uint2*>(h + (size_t)(si).y * HD + c0); \
        uint2 g2 = *reinterpret_cast<const uint2*>(h + (size_t)(si).z * HD + c0); \
        uint2 g3 = *reinterpret_cast<const uint2*>(h + (size_t)(si).w * HD + c0); \
        addpk(a0, a1, g0.x); addpk(a2, a3, g0.y); \
        addpk(a0, a1, g1.x); addpk(a2, a3, g1.y); \
        addpk(a0, a1, g2.x); addpk(a2, a3, g2.y); \
        addpk(a0, a1, g3.x); addpk(a2, a3, g3.y); \
    }

template <int DO_LN>
__global__ __launch_bounds__(256) void k_gather(
        const int* __restrict__ row_ptr, const int* __restrict__ csr_src,
        const float* __restrict__ dis, const unsigned short* __restrict__ h,
        const float* __restrict__ bias, const float* __restrict__ g,
        const float* __restrict__ bln, float* __restrict__ out) {
    int idx = blockIdx.x * blockDim.x + threadIdx.x;
    int n = idx >> 3, sub = idx & 7;
    if (n >= NN) return;
    int c0 = sub << 2;

    uint2 u = *reinterpret_cast<const uint2*>(h + (size_t)n * HD + c0);  // self-loop
    float a0 = 0.f, a1 = 0.f, a2 = 0.f, a3 = 0.f;
    addpk(a0, a1, u.x);
    addpk(a2, a3, u.y);

    int e = row_ptr[n], end = row_ptr[n + 1];
    while (e < end && (e & 3)) {
        int s = csr_src[e];
        uint2 hv = *reinterpret_cast<const uint2*>(h + (size_t)s * HD + c0);
        addpk(a0, a1, hv.x);
        addpk(a2, a3, hv.y);
        ++e;
    }
    for (; e + 15 < end; e += 16) {
        int4 s0 = *reinterpret_cast<const int4*>(csr_src + e);
        int4 s1 = *reinterpret_cast<const int4*>(csr_src + e + 4);
        int4 s2 = *reinterpret_cast<const int4*>(csr_src + e + 8);
        int4 s3 = *reinterpret_cast<const int4*>(csr_src + e + 12);
        uint2 g0 = *reinterpret_cast<const uint2*>(h + (size_t)s0.x * HD + c0);
        uint2 g1 = *reinterpret_cast<const uint2*>(h + (size_t)s0.y * HD + c0);
        uint2 g2 = *reinterpret_cast<const uint2*>(h + (size_t)s0.z * HD + c0);
        uint2 g3 = *reinterpret_cast<const uint2*>(h + (size_t)s0.w * HD + c0);
        uint2 g4 = *reinterpret_cast<const uint2*>(h + (size_t)s1.x * HD + c0);
        uint2 g5 = *reinterpret_cast<const uint2*>(h + (size_t)s1.y * HD + c0);
        uint2 g6 = *reinterpret_cast<const uint2*>(h + (size_t)s1.z * HD + c0);
        uint2 g7 = *reinterpret_cast<const uint2*>(h + (size_t)s1.w * HD + c0);
        uint2 g8 = *reinterpret_cast<const uint2*>(h + (size_t)s2.x * HD + c0);
        uint2 g9 = *reinterpret_cast<const uint2*>(h + (size_t)s2.y * HD + c0);
        uint2 ga = *reinterpret_cast<const uint2*>(h + (size_t)s2.z * HD + c0);
        uint2 gb = *reinterpret_cast<const uint2*>(h + (size_t)s2.w * HD + c0);
        uint2 gc = *reinterpret_cast<const uint2*>(h + (size_t)s3.x * HD + c0);
        uint2 gd = *reinterpret_cast<const uint2*>(h + (size_t)s3.y * HD + c0);
        uint2 ge = *reinterpret_cast<const uint2*>(h + (size_t)s3.z * HD + c0);
        uint2 gf = *reinterpret_cast<const uint2*>(h + (size_t)s3.w * HD + c0);
        addpk(a0, a1, g0.x); addpk(a2, a3, g0.y);
        addpk(a0, a1, g1.x); addpk(a2, a3, g1.y);
        addpk(a0, a1, g2.x); addpk(a2, a3, g2.y);
        addpk(a0, a1, g3.x); addpk(a2, a3, g3.y);
        addpk(a0, a1, g4.x); addpk(a2, a3, g4.y);
        addpk(a0, a1, g5.x); addpk(a2, a3, g5.y);
        addpk(a0, a1, g6.x); addpk(a2, a3, g6.y);
        addpk(a0, a1, g7.x); addpk(a2, a3, g7.y);
        addpk(a0, a1, g8.x); addpk(a2, a3, g8.y);
        addpk(a0, a1, g9.x); addpk(a2, a3, g9.y);
        addpk(a0, a1, ga.x); addpk(a2, a3, ga.y);
        addpk(a0, a1, gb.x); addpk(a2, a3, gb.y);
        addpk(a0, a1, gc.x); addpk(a2, a3, gc.y);
        addpk(a0, a1, gd.x); addpk(a2, a3, gd.y);
        addpk(a0, a1, ge.x); addpk(a2, a3, ge.y);
        addpk(a0, a1, gf.x); addpk(a2, a3, gf.y);
    }
    if (e + 7 < end) {
        int4 s0 = *reinterpret_cast<const int4*>(csr_src + e);
        int4 s1 = *reinterpret_cast<const int4*>(csr_src + e + 4);
        G4(s0);
        G4(s1);
        e += 8;
    }
    if (e + 3 < end) {
        int4 s0 = *reinterpret_cast<const int4*>(csr_src + e);
        G4(s0);
        e += 4;
    }
    for (; e < end; ++e) {
        int s = csr_src[e];
        uint2 hv = *reinterpret_cast<const uint2*>(h + (size_t)s * HD + c0);
        addpk(a0, a1, hv.x);
        addpk(a2, a3, hv.y);
    }

    float d = dis[n];
    float4 bv = *reinterpret_cast<const float4*>(bias + c0);
    float v0 = fmaxf(fmaf(a0, d, bv.x), 0.f);
    float v1 = fmaxf(fmaf(a1, d, bv.y), 0.f);
    float v2 = fmaxf(fmaf(a2, d, bv.z), 0.f);
    float v3 = fmaxf(fmaf(a3, d, bv.w), 0.f);

    if (DO_LN) {
        float s = (v0 + v1) + (v2 + v3);
        float s2 = (v0 * v0 + v1 * v1) + (v2 * v2 + v3 * v3);
#pragma unroll
        for (int m = 4; m >= 1; m >>= 1) {
            s += __shfl_xor(s, m, 8);
            s2 += __shfl_xor(s2, m, 8);
        }
        float mean = s * (1.f / 32.f);
        float var = s2 * (1.f / 32.f) - mean * mean;
        float r = rsqrtf(var + LN_EPS);
        float4 gv = *reinterpret_cast<const float4*>(g + c0);
        float4 lb = *reinterpret_cast<const float4*>(bln + c0);
        v0 = (v0 - mean) * r * gv.x + lb.x;
        v1 = (v1 - mean) * r * gv.y + lb.y;
        v2 = (v2 - mean) * r * gv.z + lb.z;
        v3 = (v3 - mean) * r * gv.w + lb.w;
    }
    float4_v ov;
    ov[0] = v0; ov[1] = v1; ov[2] = v2; ov[3] = v3;
    __builtin_nontemporal_store(ov, reinterpret_cast<float4_v*>(out + (size_t)n * HD + c0));
}

// ---------------- final: MLP head + log_softmax ----------------

__global__ void k_final(const float* __restrict__ hin,
                        const float* __restrict__ w1, const float* __restrict__ mb1,
                        const float* __restrict__ w2, const float* __restrict__ mb2,
                        float* __restrict__ out) {
    __shared__ float sw1[HD * MID], sw2[MID * OUTD], sb1[MID], sb2[OUTD];
    for (int t = threadIdx.x; t < HD * MID; t += blockDim.x) sw1[t] = w1[t];
    for (int t = threadIdx.x; t < MID * OUTD; t += blockDim.x) sw2[t] = w2[t];
    if (threadIdx.x < MID) sb1[threadIdx.x] = mb1[threadIdx.x];
    if (threadIdx.x < OUTD) sb2[threadIdx.x] = mb2[threadIdx.x];
    __syncthreads();
    int n = blockIdx.x * blockDim.x + threadIdx.x;
    if (n >= NN) return;
    float h[HD];
    const float* ar = hin + (size_t)n * HD;
#pragma unroll
    for (int k = 0; k < HD; ++k) h[k] = ar[k];
    float t[MID];
#pragma unroll
    for (int j = 0; j < MID; ++j) {
        float a = sb1[j];
#pragma unroll
        for (int k = 0; k < HD; ++k) a += h[k] * sw1[k * MID + j];
        t[j] = fmaxf(a, 0.f);
    }
    float o[OUTD];
#pragma unroll
    for (int j = 0; j < OUTD; ++j) {
        float a = sb2[j];
#pragma unroll
        for (int k = 0; k < MID; ++k) a += t[k] * sw2[k * OUTD + j];
        o[j] = a;
    }
    float mx = o[0];
#pragma unroll
    for (int j = 1; j < OUTD; ++j) mx = fmaxf(mx, o[j]);
    float se = 0.f;
#pragma unroll
    for (int j = 0; j < OUTD; ++j) se += __expf(o[j] - mx);
    float lse = __logf(se) + mx;
    float* orow = out + (size_t)n * OUTD;
#pragma unroll
    for (int j = 0; j < OUTD; ++j) orow[j] = o[j] - lse;
}

// ---------------- launch ----------------

extern "C" void kernel_launch(void* const* d_in, const int* in_sizes, int n_in,
                              void* d_out, int out_size, void* d_ws, size_t ws_size,
                              hipStream_t stream) {
    const float* x     = (const float*)d_in[0];
    const int*   ei    = (const int*)d_in[1];
    const float* W0    = (const float*)d_in[2];
    const float* b0    = (const float*)d_in[3];
    const float* W1    = (const float*)d_in[4];
    const float* b1    = (const float*)d_in[5];
    const float* W2    = (const float*)d_in[6];
    const float* b2    = (const float*)d_in[7];
    const float* ln0_g = (const float*)d_in[8];
    const float* ln0_b = (const float*)d_in[9];
    const float* ln1_g = (const float*)d_in[10];
    const float* ln1_b = (const float*)d_in[11];
    const float* mp_w1 = (const float*)d_in[12];
    const float* mp_b1 = (const float*)d_in[13];
    const float* mp_w2 = (const float*)d_in[14];
    const float* mp_b2 = (const float*)d_in[15];
    float* out = (float*)d_out;

    const int* src = ei;        // edge_index[0]
    const int* dst = ei + NE;   // edge_index[1]

    char* w = (char*)d_ws;
    auto align256 = [](size_t v) { return (v + 255) & ~(size_t)255; };
    int* g_bincur  = (int*)w;   w += align256((size_t)NB * 4);
    int* g_binexcl = (int*)w;   w += align256((size_t)NB * 4);
    int* row_ptr   = (int*)w;   w += align256((size_t)(NN + 1) * 4);
    float* dis     = (float*)w; w += align256((size_t)NN * 4);
    char* uni = w;              // union region (staging vs activations)
    unsigned short* bufB = (unsigned short*)uni;                  // bf16 hs, 6.4 MB
    float* bufA = (float*)(uni + align256((size_t)NN * HD * 2));  // f32 acts, 12.8 MB
    unsigned int* staged = (unsigned int*)uni;                    // NB*CAP*4 = 16.0 MB
    size_t uni_sz = align256((size_t)NB * CAP * 4);
    size_t uni_sz2 = align256((size_t)NN * HD * 2) + align256((size_t)NN * HD * 4);
    w = uni + (uni_sz > uni_sz2 ? uni_sz : uni_sz2);
    int* csr_src = (int*)w;

    const int BS = 256;
    int gN  = (NN + BS - 1) / BS;           // 391
    int gA  = (NE + EPB - 1) / EPB;         // 391
    int gN8 = (NN * 8 + BS - 1) / BS;       // 3125
    int gG  = (NN + 63) / 64;               // 1563

    // CSR build (binned counting sort)
    k_zero_bins<<<1, 512, 0, stream>>>(g_bincur);
    k_binA<<<gA, ABS, 0, stream>>>(src, dst, g_bincur, staged);
    k_binscan<<<1, 512, 0, stream>>>(g_bincur, g_binexcl, row_ptr);
    k_binC<<<NB, CBS, 0, stream>>>(g_bincur, g_binexcl, staged, row_ptr, dis, csr_src);

    // layer 0 (MFMA)
    k_gemm_mfma<DIN><<<gG, BS, 0, stream>>>(x, W0, dis, bufB);
    k_gather<1><<<gN8, BS, 0, stream>>>(row_ptr, csr_src, dis, bufB, b0,
                                        ln0_g, ln0_b, bufA);
    // layer 1
    k_gemm<HD><<<gG, BS, 0, stream>>>(bufA, W1, dis, bufB);
    k_gather<1><<<gN8, BS, 0, stream>>>(row_ptr, csr_src, dis, bufB, b1,
                                        ln1_g, ln1_b, bufA);
    // layer 2 (no LN)
    k_gemm<HD><<<gG, BS, 0, stream>>>(bufA, W2, dis, bufB);
    k_gather<0><<<gN8, BS, 0, stream>>>(row_ptr, csr_src, dis, bufB, b2,
                                        nullptr, nullptr, bufA);

    // head
    k_final<<<gN, BS, 0, stream>>>(bufA, mp_w1, mp_b1, mp_w2, mp_b2, out);
}

// Round 16
// 215.788 us; speedup vs baseline: 1.5820x; 1.1021x over previous
//
#include <hip/hip_runtime.h>

#define NN 100000
#define NE 3200000
#define DIN 128
#define HD 32
#define MID 16
#define OUTD 8
#define LN_EPS 1e-5f

#define BINSHIFT 8                 // 256 nodes per bin
#define NB 391                     // ceil(NN / 256)
#define CAP 10240                  // bin capacity (mean 8192)
#define EPB 8192                   // edges per pass-A block
#define ABS 1024                   // pass-A block size (16 waves/block)
#define AITER (EPB / ABS)          // 8
#define CBS 1024                   // pass-C block size

// true clang vector types
typedef float float4_v __attribute__((ext_vector_type(4)));
typedef short short8   __attribute__((ext_vector_type(8)));
typedef float f32x4    __attribute__((ext_vector_type(4)));

// ---------------- bf16 helpers ----------------

__device__ __forceinline__ float bf2f(unsigned short u) {
    union { unsigned int i; float f; } c;
    c.i = ((unsigned int)u) << 16;
    return c.f;
}
__device__ __forceinline__ unsigned short f2bf(float f) {
    union { float f; unsigned int i; } c;
    c.f = f;
    unsigned int r = c.i + 0x7FFFu + ((c.i >> 16) & 1u);  // RNE
    return (unsigned short)(r >> 16);
}
__device__ __forceinline__ unsigned int pack2(float a, float b) {
    return (unsigned int)f2bf(a) | ((unsigned int)f2bf(b) << 16);
}
__device__ __forceinline__ void addpk(float& a0, float& a1, unsigned int u) {
    union { unsigned int i; float f; } lo, hi;
    lo.i = u << 16;
    hi.i = u & 0xFFFF0000u;
    a0 += lo.f;
    a1 += hi.f;
}

// ---------------- binned CSR build ----------------

__global__ void k_zero_bins(int* __restrict__ g_bincur) {
    int i = blockIdx.x * blockDim.x + threadIdx.x;
    if (i < NB) g_bincur[i] = 0;
}

__global__ __launch_bounds__(ABS) void k_binA(const int* __restrict__ src,
                                              const int* __restrict__ dst,
                                              int* __restrict__ g_bincur,
                                              unsigned int* __restrict__ staged) {
    __shared__ int cnt[512];              // histogram -> cursor
    __shared__ int obin[512];             // intra-block exclusive offsets
    __shared__ int base[NB];              // global reserved base per bin
    __shared__ unsigned short sbin[EPB];  // slot -> bin
    __shared__ unsigned int sedge[EPB];   // packed edges, bin-grouped
    int tid = threadIdx.x;
    if (tid < 512) cnt[tid] = 0;
    __syncthreads();
    int e0 = blockIdx.x * EPB;
    int total = min(EPB, NE - e0);
    int dreg[AITER];
#pragma unroll
    for (int i = 0; i < AITER; ++i) {
        int e = e0 + i * ABS + tid;
        dreg[i] = (e < NE) ? dst[e] : -1;
        if (dreg[i] >= 0) atomicAdd(&cnt[dreg[i] >> BINSHIFT], 1);
    }
    __syncthreads();
    int v = 0;
    if (tid < 512) {
        v = cnt[tid];
        obin[tid] = v;
    }
    __syncthreads();
#pragma unroll
    for (int off = 1; off < 512; off <<= 1) {
        int t = (tid < 512 && tid >= off) ? obin[tid - off] : 0;
        __syncthreads();
        if (tid < 512) obin[tid] += t;
        __syncthreads();
    }
    if (tid < 512) obin[tid] -= v;  // exclusive
    __syncthreads();
    if (tid < NB) {
        int c = cnt[tid];
        base[tid] = c ? atomicAdd(&g_bincur[tid], c) : 0;
        int s0 = obin[tid];
        for (int k = 0; k < c; ++k) sbin[s0 + k] = (unsigned short)tid;
    }
    if (tid < 512) cnt[tid] = 0;
    __syncthreads();
#pragma unroll
    for (int i = 0; i < AITER; ++i) {
        int e = e0 + i * ABS + tid;
        int d = dreg[i];
        if (d >= 0) {
            int b = d >> BINSHIFT;
            int slot = obin[b] + atomicAdd(&cnt[b], 1);
            sedge[slot] = ((unsigned int)(d & 255) << 24) | (unsigned int)src[e];
        }
    }
    __syncthreads();
#pragma unroll
    for (int i = 0; i < AITER; ++i) {
        int s = i * ABS + tid;
        if (s < total) {
            int b = sbin[s];
            int k = base[b] + (s - obin[b]);
            if (k < CAP) staged[(size_t)b * CAP + k] = sedge[s];
        }
    }
}

__global__ void k_binscan(const int* __restrict__ g_bincur, int* __restrict__ g_binexcl,
                          int* __restrict__ row_ptr) {
    __shared__ int s[512];
    int v = (threadIdx.x < NB) ? min(g_bincur[threadIdx.x], CAP) : 0;
    s[threadIdx.x] = v;
    __syncthreads();
#pragma unroll
    for (int off = 1; off < 512; off <<= 1) {
        int t = (threadIdx.x >= off) ? s[threadIdx.x - off] : 0;
        __syncthreads();
        s[threadIdx.x] += t;
        __syncthreads();
    }
    if (threadIdx.x < NB) g_binexcl[threadIdx.x] = s[threadIdx.x] - v;
    if (threadIdx.x == NB - 1) row_ptr[NN] = s[threadIdx.x];
}

__global__ __launch_bounds__(CBS) void k_binC(const int* __restrict__ g_bincur,
                                              const int* __restrict__ g_binexcl,
                                              const unsigned int* __restrict__ staged,
                                              int* __restrict__ row_ptr,
                                              float* __restrict__ dis,
                                              int* __restrict__ csr_src) {
    __shared__ int cnt[256];
    __shared__ int scn[256];
    int b = blockIdx.x;
    int tid = threadIdx.x;
    int tot = min(g_bincur[b], CAP);
    if (tid < 256) cnt[tid] = 0;
    __syncthreads();
    const unsigned int* st = staged + (size_t)b * CAP;
    for (int i = tid; i < tot; i += CBS)
        atomicAdd(&cnt[st[i] >> 24], 1);
    __syncthreads();
    int v = 0;
    if (tid < 256) {
        v = cnt[tid];
        scn[tid] = v;
    }
    __syncthreads();
#pragma unroll
    for (int off = 1; off < 256; off <<= 1) {
        int t = (tid < 256 && tid >= off) ? scn[tid - off] : 0;
        __syncthreads();
        if (tid < 256) scn[tid] += t;
        __syncthreads();
    }
    int gbase = g_binexcl[b];
    if (tid < 256) {
        int excl = scn[tid] - v;
        int node = (b << BINSHIFT) + tid;
        if (node < NN) {
            row_ptr[node] = gbase + excl;
            dis[node] = rsqrtf((float)(v + 1));  // +1 self-loop
        }
        cnt[tid] = excl;  // reuse as scatter cursor
    }
    __syncthreads();
    for (int i = tid; i < tot; i += CBS) {
        unsigned int p = st[i];
        int rank = atomicAdd(&cnt[p >> 24], 1);
        csr_src[gbase + rank] = (int)(p & 0xFFFFFFu);
    }
}

// ---------------- layer-0 GEMM via MFMA ----------------

template <int K>
__global__ __launch_bounds__(256) void k_gemm_mfma(const float* __restrict__ x,
                                                   const float* __restrict__ W,
                                                   const float* __restrict__ dis,
                                                   unsigned short* __restrict__ hs) {
    constexpr int XP = K + 8;
    __shared__ unsigned short xb[64 * XP];
    __shared__ unsigned short wt[HD * XP];   // W^T: [j][k]
    __shared__ float sdis[64];
    int tid = threadIdx.x;
    int n0 = blockIdx.x * 64;
    for (int f = tid; f < K * HD; f += 256) {
        int k = f >> 5, j = f & 31;
        wt[j * XP + k] = f2bf(W[f]);
    }
    if (tid < 64) {
        int nn = n0 + tid;
        sdis[tid] = dis[nn < NN ? nn : NN - 1];
    }
    constexpr int FQ = K / 4;
    for (int f = tid; f < 64 * FQ; f += 256) {
        int node = f / FQ, kq = f % FQ;
        int nn = n0 + node;
        if (nn < NN) {
            float4 xv = *reinterpret_cast<const float4*>(x + (size_t)nn * K + kq * 4);
            unsigned short* p = &xb[node * XP + kq * 4];
            p[0] = f2bf(xv.x);
            p[1] = f2bf(xv.y);
            p[2] = f2bf(xv.z);
            p[3] = f2bf(xv.w);
        }
    }
    __syncthreads();
    int w = tid >> 6, l = tid & 63;
    int arow = l & 15, kg = l >> 4;
    f32x4 acc0 = {0.f, 0.f, 0.f, 0.f};
    f32x4 acc1 = {0.f, 0.f, 0.f, 0.f};
#pragma unroll
    for (int ks = 0; ks < K / 32; ++ks) {
        short8 a  = *reinterpret_cast<const short8*>(&xb[(w * 16 + arow) * XP + ks * 32 + kg * 8]);
        short8 b0 = *reinterpret_cast<const short8*>(&wt[arow * XP + ks * 32 + kg * 8]);
        short8 b1 = *reinterpret_cast<const short8*>(&wt[(16 + arow) * XP + ks * 32 + kg * 8]);
        acc0 = __builtin_amdgcn_mfma_f32_16x16x32_bf16(a, b0, acc0, 0, 0, 0);
        acc1 = __builtin_amdgcn_mfma_f32_16x16x32_bf16(a, b1, acc1, 0, 0, 0);
    }
#pragma unroll
    for (int r = 0; r < 4; ++r) {
        int nloc = w * 16 + kg * 4 + r;
        int nn = n0 + nloc;
        if (nn < NN) {
            float d = sdis[nloc];
            hs[(size_t)nn * HD + arow]      = f2bf(acc0[r] * d);
            hs[(size_t)nn * HD + 16 + arow] = f2bf(acc1[r] * d);
        }
    }
}

// ---------------- fused gather (+bias/relu[/LN][/next-layer GEMM]) ----------------
// 8 lanes/node, 4 ch/lane. If DO_GEMM: epilogue computes y = v @ Wn via
// __shfl broadcast (wave-synchronous) + LDS W, writes bf16 hs_next * dis.
// Else: writes f32 out.

#define G4(si) \
    { \
        uint2 g0 = *reinterpret_cast<const uint2*>(h + (size_t)(si).x * HD + c0); \
        uint2 g1 = *reinterpret_cast<const uint2*>(h + (size_t)(si).y * HD + c0); \
        uint2 g2 = *reinterpret_cast<const uint2*>(h + (size_t)(si).z * HD + c0); \
        uint2 g3 = *reinterpret_cast<const uint2*>(h + (size_t)(si).w * HD + c0); \
        addpk(a0, a1, g0.x); addpk(a2, a3, g0.y); \
        addpk(a0, a1, g1.x); addpk(a2, a3, g1.y); \
        addpk(a0, a1, g2.x); addpk(a2, a3, g2.y); \
        addpk(a0, a1, g3.x); addpk(a2, a3, g3.y); \
    }

template <int DO_LN, int DO_GEMM>
__global__ __launch_bounds__(256) void k_gather(
        const int* __restrict__ row_ptr, const int* __restrict__ csr_src,
        const float* __restrict__ dis, const unsigned short* __restrict__ h,
        const float* __restrict__ bias, const float* __restrict__ g,
        const float* __restrict__ bln, const float* __restrict__ Wn,
        float* __restrict__ outf, unsigned short* __restrict__ outh) {
    __shared__ float sW[HD * HD];  // only used when DO_GEMM
    if (DO_GEMM) {
        for (int t = threadIdx.x; t < HD * HD; t += 256) sW[t] = Wn[t];
        __syncthreads();  // before any divergence/return
    }
    int idx = blockIdx.x * blockDim.x + threadIdx.x;
    int n = idx >> 3, sub = idx & 7;
    if (n >= NN) return;
    int c0 = sub << 2;

    uint2 u = *reinterpret_cast<const uint2*>(h + (size_t)n * HD + c0);  // self-loop
    float a0 = 0.f, a1 = 0.f, a2 = 0.f, a3 = 0.f;
    addpk(a0, a1, u.x);
    addpk(a2, a3, u.y);

    int e = row_ptr[n], end = row_ptr[n + 1];
    while (e < end && (e & 3)) {
        int s = csr_src[e];
        uint2 hv = *reinterpret_cast<const uint2*>(h + (size_t)s * HD + c0);
        addpk(a0, a1, hv.x);
        addpk(a2, a3, hv.y);
        ++e;
    }
    for (; e + 15 < end; e += 16) {
        int4 s0 = *reinterpret_cast<const int4*>(csr_src + e);
        int4 s1 = *reinterpret_cast<const int4*>(csr_src + e + 4);
        int4 s2 = *reinterpret_cast<const int4*>(csr_src + e + 8);
        int4 s3 = *reinterpret_cast<const int4*>(csr_src + e + 12);
        uint2 g0 = *reinterpret_cast<const uint2*>(h + (size_t)s0.x * HD + c0);
        uint2 g1 = *reinterpret_cast<const uint2*>(h + (size_t)s0.y * HD + c0);
        uint2 g2 = *reinterpret_cast<const uint2*>(h + (size_t)s0.z * HD + c0);
        uint2 g3 = *reinterpret_cast<const uint2*>(h + (size_t)s0.w * HD + c0);
        uint2 g4 = *reinterpret_cast<const uint2*>(h + (size_t)s1.x * HD + c0);
        uint2 g5 = *reinterpret_cast<const uint2*>(h + (size_t)s1.y * HD + c0);
        uint2 g6 = *reinterpret_cast<const uint2*>(h + (size_t)s1.z * HD + c0);
        uint2 g7 = *reinterpret_cast<const uint2*>(h + (size_t)s1.w * HD + c0);
        uint2 g8 = *reinterpret_cast<const uint2*>(h + (size_t)s2.x * HD + c0);
        uint2 g9 = *reinterpret_cast<const uint2*>(h + (size_t)s2.y * HD + c0);
        uint2 ga = *reinterpret_cast<const uint2*>(h + (size_t)s2.z * HD + c0);
        uint2 gb = *reinterpret_cast<const uint2*>(h + (size_t)s2.w * HD + c0);
        uint2 gc = *reinterpret_cast<const uint2*>(h + (size_t)s3.x * HD + c0);
        uint2 gd = *reinterpret_cast<const uint2*>(h + (size_t)s3.y * HD + c0);
        uint2 ge = *reinterpret_cast<const uint2*>(h + (size_t)s3.z * HD + c0);
        uint2 gf = *reinterpret_cast<const uint2*>(h + (size_t)s3.w * HD + c0);
        addpk(a0, a1, g0.x); addpk(a2, a3, g0.y);
        addpk(a0, a1, g1.x); addpk(a2, a3, g1.y);
        addpk(a0, a1, g2.x); addpk(a2, a3, g2.y);
        addpk(a0, a1, g3.x); addpk(a2, a3, g3.y);
        addpk(a0, a1, g4.x); addpk(a2, a3, g4.y);
        addpk(a0, a1, g5.x); addpk(a2, a3, g5.y);
        addpk(a0, a1, g6.x); addpk(a2, a3, g6.y);
        addpk(a0, a1, g7.x); addpk(a2, a3, g7.y);
        addpk(a0, a1, g8.x); addpk(a2, a3, g8.y);
        addpk(a0, a1, g9.x); addpk(a2, a3, g9.y);
        addpk(a0, a1, ga.x); addpk(a2, a3, ga.y);
        addpk(a0, a1, gb.x); addpk(a2, a3, gb.y);
        addpk(a0, a1, gc.x); addpk(a2, a3, gc.y);
        addpk(a0, a1, gd.x); addpk(a2, a3, gd.y);
        addpk(a0, a1, ge.x); addpk(a2, a3, ge.y);
        addpk(a0, a1, gf.x); addpk(a2, a3, gf.y);
    }
    if (e + 7 < end) {
        int4 s0 = *reinterpret_cast<const int4*>(csr_src + e);
        int4 s1 = *reinterpret_cast<const int4*>(csr_src + e + 4);
        G4(s0);
        G4(s1);
        e += 8;
    }
    if (e + 3 < end) {
        int4 s0 = *reinterpret_cast<const int4*>(csr_src + e);
        G4(s0);
        e += 4;
    }
    for (; e < end; ++e) {
        int s = csr_src[e];
        uint2 hv = *reinterpret_cast<const uint2*>(h + (size_t)s * HD + c0);
        addpk(a0, a1, hv.x);
        addpk(a2, a3, hv.y);
    }

    float d = dis[n];
    float4 bv = *reinterpret_cast<const float4*>(bias + c0);
    float v0 = fmaxf(fmaf(a0, d, bv.x), 0.f);
    float v1 = fmaxf(fmaf(a1, d, bv.y), 0.f);
    float v2 = fmaxf(fmaf(a2, d, bv.z), 0.f);
    float v3 = fmaxf(fmaf(a3, d, bv.w), 0.f);

    if (DO_LN) {
        float s = (v0 + v1) + (v2 + v3);
        float s2 = (v0 * v0 + v1 * v1) + (v2 * v2 + v3 * v3);
#pragma unroll
        for (int m = 4; m >= 1; m >>= 1) {
            s += __shfl_xor(s, m, 8);
            s2 += __shfl_xor(s2, m, 8);
        }
        float mean = s * (1.f / 32.f);
        float var = s2 * (1.f / 32.f) - mean * mean;
        float r = rsqrtf(var + LN_EPS);
        float4 gv = *reinterpret_cast<const float4*>(g + c0);
        float4 lb = *reinterpret_cast<const float4*>(bln + c0);
        v0 = (v0 - mean) * r * gv.x + lb.x;
        v1 = (v1 - mean) * r * gv.y + lb.y;
        v2 = (v2 - mean) * r * gv.z + lb.z;
        v3 = (v3 - mean) * r * gv.w + lb.w;
    }

    if (DO_GEMM) {
        // y_j (j = c0..c0+3) = sum_k v_k * Wn[k][j]; v broadcast via shfl.
        float y0 = 0.f, y1 = 0.f, y2 = 0.f, y3 = 0.f;
#pragma unroll
        for (int m = 0; m < 8; ++m) {
            float vk0 = __shfl(v0, m, 8);  // channel 4m+0
            float vk1 = __shfl(v1, m, 8);
            float vk2 = __shfl(v2, m, 8);
            float vk3 = __shfl(v3, m, 8);
            float4 w0 = *reinterpret_cast<const float4*>(&sW[(4 * m + 0) * HD + c0]);
            float4 w1 = *reinterpret_cast<const float4*>(&sW[(4 * m + 1) * HD + c0]);
            float4 w2 = *reinterpret_cast<const float4*>(&sW[(4 * m + 2) * HD + c0]);
            float4 w3 = *reinterpret_cast<const float4*>(&sW[(4 * m + 3) * HD + c0]);
            y0 = fmaf(vk0, w0.x, fmaf(vk1, w1.x, fmaf(vk2, w2.x, fmaf(vk3, w3.x, y0))));
            y1 = fmaf(vk0, w0.y, fmaf(vk1, w1.y, fmaf(vk2, w2.y, fmaf(vk3, w3.y, y1))));
            y2 = fmaf(vk0, w0.z, fmaf(vk1, w1.z, fmaf(vk2, w2.z, fmaf(vk3, w3.z, y2))));
            y3 = fmaf(vk0, w0.w, fmaf(vk1, w1.w, fmaf(vk2, w2.w, fmaf(vk3, w3.w, y3))));
        }
        uint2 pp;
        pp.x = pack2(y0 * d, y1 * d);
        pp.y = pack2(y2 * d, y3 * d);
        *reinterpret_cast<uint2*>(outh + (size_t)n * HD + c0) = pp;
    } else {
        float4_v ov;
        ov[0] = v0; ov[1] = v1; ov[2] = v2; ov[3] = v3;
        __builtin_nontemporal_store(ov, reinterpret_cast<float4_v*>(outf + (size_t)n * HD + c0));
    }
}

// ---------------- final: MLP head + log_softmax ----------------

__global__ void k_final(const float* __restrict__ hin,
                        const float* __restrict__ w1, const float* __restrict__ mb1,
                        const float* __restrict__ w2, const float* __restrict__ mb2,
                        float* __restrict__ out) {
    __shared__ float sw1[HD * MID], sw2[MID * OUTD], sb1[MID], sb2[OUTD];
    for (int t = threadIdx.x; t < HD * MID; t += blockDim.x) sw1[t] = w1[t];
    for (int t = threadIdx.x; t < MID * OUTD; t += blockDim.x) sw2[t] = w2[t];
    if (threadIdx.x < MID) sb1[threadIdx.x] = mb1[threadIdx.x];
    if (threadIdx.x < OUTD) sb2[threadIdx.x] = mb2[threadIdx.x];
    __syncthreads();
    int n = blockIdx.x * blockDim.x + threadIdx.x;
    if (n >= NN) return;
    float h[HD];
    const float* ar = hin + (size_t)n * HD;
#pragma unroll
    for (int k = 0; k < HD; ++k) h[k] = ar[k];
    float t[MID];
#pragma unroll
    for (int j = 0; j < MID; ++j) {
        float a = sb1[j];
#pragma unroll
        for (int k = 0; k < HD; ++k) a += h[k] * sw1[k * MID + j];
        t[j] = fmaxf(a, 0.f);
    }
    float o[OUTD];
#pragma unroll
    for (int j = 0; j < OUTD; ++j) {
        float a = sb2[j];
#pragma unroll
        for (int k = 0; k < MID; ++k) a += t[k] * sw2[k * OUTD + j];
        o[j] = a;
    }
    float mx = o[0];
#pragma unroll
    for (int j = 1; j < OUTD; ++j) mx = fmaxf(mx, o[j]);
    float se = 0.f;
#pragma unroll
    for (int j = 0; j < OUTD; ++j) se += __expf(o[j] - mx);
    float lse = __logf(se) + mx;
    float* orow = out + (size_t)n * OUTD;
#pragma unroll
    for (int j = 0; j < OUTD; ++j) orow[j] = o[j] - lse;
}

// ---------------- launch ----------------

extern "C" void kernel_launch(void* const* d_in, const int* in_sizes, int n_in,
                              void* d_out, int out_size, void* d_ws, size_t ws_size,
                              hipStream_t stream) {
    const float* x     = (const float*)d_in[0];
    const int*   ei    = (const int*)d_in[1];
    const float* W0    = (const float*)d_in[2];
    const float* b0    = (const float*)d_in[3];
    const float* W1    = (const float*)d_in[4];
    const float* b1    = (const float*)d_in[5];
    const float* W2    = (const float*)d_in[6];
    const float* b2    = (const float*)d_in[7];
    const float* ln0_g = (const float*)d_in[8];
    const float* ln0_b = (const float*)d_in[9];
    const float* ln1_g = (const float*)d_in[10];
    const float* ln1_b = (const float*)d_in[11];
    const float* mp_w1 = (const float*)d_in[12];
    const float* mp_b1 = (const float*)d_in[13];
    const float* mp_w2 = (const float*)d_in[14];
    const float* mp_b2 = (const float*)d_in[15];
    float* out = (float*)d_out;

    const int* src = ei;        // edge_index[0]
    const int* dst = ei + NE;   // edge_index[1]

    char* w = (char*)d_ws;
    auto align256 = [](size_t v) { return (v + 255) & ~(size_t)255; };
    int* g_bincur  = (int*)w;   w += align256((size_t)NB * 4);
    int* g_binexcl = (int*)w;   w += align256((size_t)NB * 4);
    int* row_ptr   = (int*)w;   w += align256((size_t)(NN + 1) * 4);
    float* dis     = (float*)w; w += align256((size_t)NN * 4);
    char* uni = w;              // union region (staging vs activations)
    size_t hs_sz = align256((size_t)NN * HD * 2);
    unsigned short* hs0 = (unsigned short*)uni;                 // bf16, 6.4 MB
    unsigned short* hs1 = (unsigned short*)(uni + hs_sz);       // bf16, 6.4 MB
    float* bufA = (float*)(uni + 2 * hs_sz);                    // f32, 12.8 MB
    unsigned int* staged = (unsigned int*)uni;                  // 16.0 MB (build only)
    size_t uni_sz = align256((size_t)NB * CAP * 4);
    size_t uni_sz2 = 2 * hs_sz + align256((size_t)NN * HD * 4);
    w = uni + (uni_sz > uni_sz2 ? uni_sz : uni_sz2);
    int* csr_src = (int*)w;

    const int BS = 256;
    int gN  = (NN + BS - 1) / BS;           // 391
    int gA  = (NE + EPB - 1) / EPB;         // 391
    int gN8 = (NN * 8 + BS - 1) / BS;       // 3125
    int gG  = (NN + 63) / 64;               // 1563

    // CSR build (binned counting sort)
    k_zero_bins<<<1, 512, 0, stream>>>(g_bincur);
    k_binA<<<gA, ABS, 0, stream>>>(src, dst, g_bincur, staged);
    k_binscan<<<1, 512, 0, stream>>>(g_bincur, g_binexcl, row_ptr);
    k_binC<<<NB, CBS, 0, stream>>>(g_bincur, g_binexcl, staged, row_ptr, dis, csr_src);

    // layer 0 GEMM (MFMA) -> hs0
    k_gemm_mfma<DIN><<<gG, BS, 0, stream>>>(x, W0, dis, hs0);
    // layer 0 gather + LN + layer-1 GEMM fused -> hs1
    k_gather<1, 1><<<gN8, BS, 0, stream>>>(row_ptr, csr_src, dis, hs0, b0,
                                           ln0_g, ln0_b, W1, nullptr, hs1);
    // layer 1 gather + LN + layer-2 GEMM fused -> hs0
    k_gather<1, 1><<<gN8, BS, 0, stream>>>(row_ptr, csr_src, dis, hs1, b1,
                                           ln1_g, ln1_b, W2, nullptr, hs0);
    // layer 2 gather (no LN, no GEMM) -> bufA f32
    k_gather<0, 0><<<gN8, BS, 0, stream>>>(row_ptr, csr_src, dis, hs0, b2,
                                           nullptr, nullptr, nullptr, bufA, nullptr);

    // head
    k_final<<<gN, BS, 0, stream>>>(bufA, mp_w1, mp_b1, mp_w2, mp_b2, out);
}

// Round 17
// 211.112 us; speedup vs baseline: 1.6170x; 1.0222x over previous
//
#include <hip/hip_runtime.h>

#define NN 100000
#define NE 3200000
#define DIN 128
#define HD 32
#define MID 16
#define OUTD 8
#define LN_EPS 1e-5f

#define BINSHIFT 8                 // 256 nodes per bin
#define NB 391                     // ceil(NN / 256)
#define CAP 10240                  // bin capacity (mean 8192)
#define EPB 8192                   // edges per pass-A block
#define ABS 1024                   // pass-A block size (16 waves/block)
#define AITER (EPB / ABS)          // 8
#define CBS 1024                   // pass-C block size
#define GBS 64                     // gather block size (1 wave, 8 nodes)

// true clang vector types
typedef float float4_v __attribute__((ext_vector_type(4)));
typedef short short8   __attribute__((ext_vector_type(8)));
typedef float f32x4    __attribute__((ext_vector_type(4)));

// ---------------- bf16 helpers ----------------

__device__ __forceinline__ float bf2f(unsigned short u) {
    union { unsigned int i; float f; } c;
    c.i = ((unsigned int)u) << 16;
    return c.f;
}
__device__ __forceinline__ unsigned short f2bf(float f) {
    union { float f; unsigned int i; } c;
    c.f = f;
    unsigned int r = c.i + 0x7FFFu + ((c.i >> 16) & 1u);  // RNE
    return (unsigned short)(r >> 16);
}
__device__ __forceinline__ unsigned int pack2(float a, float b) {
    return (unsigned int)f2bf(a) | ((unsigned int)f2bf(b) << 16);
}
__device__ __forceinline__ void addpk(float& a0, float& a1, unsigned int u) {
    union { unsigned int i; float f; } lo, hi;
    lo.i = u << 16;
    hi.i = u & 0xFFFF0000u;
    a0 += lo.f;
    a1 += hi.f;
}

// ---------------- binned CSR build ----------------

__global__ void k_zero_bins(int* __restrict__ g_bincur) {
    int i = blockIdx.x * blockDim.x + threadIdx.x;
    if (i < NB) g_bincur[i] = 0;
}

__global__ __launch_bounds__(ABS) void k_binA(const int* __restrict__ src,
                                              const int* __restrict__ dst,
                                              int* __restrict__ g_bincur,
                                              unsigned int* __restrict__ staged) {
    __shared__ int cnt[512];              // histogram -> cursor
    __shared__ int obin[512];             // intra-block exclusive offsets
    __shared__ int base[NB];              // global reserved base per bin
    __shared__ unsigned short sbin[EPB];  // slot -> bin
    __shared__ unsigned int sedge[EPB];   // packed edges, bin-grouped
    int tid = threadIdx.x;
    if (tid < 512) cnt[tid] = 0;
    __syncthreads();
    int e0 = blockIdx.x * EPB;
    int total = min(EPB, NE - e0);
    int dreg[AITER];
#pragma unroll
    for (int i = 0; i < AITER; ++i) {
        int e = e0 + i * ABS + tid;
        dreg[i] = (e < NE) ? dst[e] : -1;
        if (dreg[i] >= 0) atomicAdd(&cnt[dreg[i] >> BINSHIFT], 1);
    }
    __syncthreads();
    int v = 0;
    if (tid < 512) {
        v = cnt[tid];
        obin[tid] = v;
    }
    __syncthreads();
#pragma unroll
    for (int off = 1; off < 512; off <<= 1) {
        int t = (tid < 512 && tid >= off) ? obin[tid - off] : 0;
        __syncthreads();
        if (tid < 512) obin[tid] += t;
        __syncthreads();
    }
    if (tid < 512) obin[tid] -= v;  // exclusive
    __syncthreads();
    if (tid < NB) {
        int c = cnt[tid];
        base[tid] = c ? atomicAdd(&g_bincur[tid], c) : 0;
        int s0 = obin[tid];
        for (int k = 0; k < c; ++k) sbin[s0 + k] = (unsigned short)tid;
    }
    if (tid < 512) cnt[tid] = 0;
    __syncthreads();
#pragma unroll
    for (int i = 0; i < AITER; ++i) {
        int e = e0 + i * ABS + tid;
        int d = dreg[i];
        if (d >= 0) {
            int b = d >> BINSHIFT;
            int slot = obin[b] + atomicAdd(&cnt[b], 1);
            sedge[slot] = ((unsigned int)(d & 255) << 24) | (unsigned int)src[e];
        }
    }
    __syncthreads();
#pragma unroll
    for (int i = 0; i < AITER; ++i) {
        int s = i * ABS + tid;
        if (s < total) {
            int b = sbin[s];
            int k = base[b] + (s - obin[b]);
            if (k < CAP) staged[(size_t)b * CAP + k] = sedge[s];
        }
    }
}

__global__ void k_binscan(const int* __restrict__ g_bincur, int* __restrict__ g_binexcl,
                          int* __restrict__ row_ptr) {
    __shared__ int s[512];
    int v = (threadIdx.x < NB) ? min(g_bincur[threadIdx.x], CAP) : 0;
    s[threadIdx.x] = v;
    __syncthreads();
#pragma unroll
    for (int off = 1; off < 512; off <<= 1) {
        int t = (threadIdx.x >= off) ? s[threadIdx.x - off] : 0;
        __syncthreads();
        s[threadIdx.x] += t;
        __syncthreads();
    }
    if (threadIdx.x < NB) g_binexcl[threadIdx.x] = s[threadIdx.x] - v;
    if (threadIdx.x == NB - 1) row_ptr[NN] = s[threadIdx.x];
}

__global__ __launch_bounds__(CBS) void k_binC(const int* __restrict__ g_bincur,
                                              const int* __restrict__ g_binexcl,
                                              const unsigned int* __restrict__ staged,
                                              int* __restrict__ row_ptr,
                                              float* __restrict__ dis,
                                              int* __restrict__ csr_src) {
    __shared__ int cnt[256];
    __shared__ int scn[256];
    int b = blockIdx.x;
    int tid = threadIdx.x;
    int tot = min(g_bincur[b], CAP);
    if (tid < 256) cnt[tid] = 0;
    __syncthreads();
    const unsigned int* st = staged + (size_t)b * CAP;
    for (int i = tid; i < tot; i += CBS)
        atomicAdd(&cnt[st[i] >> 24], 1);
    __syncthreads();
    int v = 0;
    if (tid < 256) {
        v = cnt[tid];
        scn[tid] = v;
    }
    __syncthreads();
#pragma unroll
    for (int off = 1; off < 256; off <<= 1) {
        int t = (tid < 256 && tid >= off) ? scn[tid - off] : 0;
        __syncthreads();
        if (tid < 256) scn[tid] += t;
        __syncthreads();
    }
    int gbase = g_binexcl[b];
    if (tid < 256) {
        int excl = scn[tid] - v;
        int node = (b << BINSHIFT) + tid;
        if (node < NN) {
            row_ptr[node] = gbase + excl;
            dis[node] = rsqrtf((float)(v + 1));  // +1 self-loop
        }
        cnt[tid] = excl;  // reuse as scatter cursor
    }
    __syncthreads();
    for (int i = tid; i < tot; i += CBS) {
        unsigned int p = st[i];
        int rank = atomicAdd(&cnt[p >> 24], 1);
        csr_src[gbase + rank] = (int)(p & 0xFFFFFFu);
    }
}

// ---------------- layer-0 GEMM via MFMA ----------------

template <int K>
__global__ __launch_bounds__(256) void k_gemm_mfma(const float* __restrict__ x,
                                                   const float* __restrict__ W,
                                                   const float* __restrict__ dis,
                                                   unsigned short* __restrict__ hs) {
    constexpr int XP = K + 8;
    __shared__ unsigned short xb[64 * XP];
    __shared__ unsigned short wt[HD * XP];   // W^T: [j][k]
    __shared__ float sdis[64];
    int tid = threadIdx.x;
    int n0 = blockIdx.x * 64;
    for (int f = tid; f < K * HD; f += 256) {
        int k = f >> 5, j = f & 31;
        wt[j * XP + k] = f2bf(W[f]);
    }
    if (tid < 64) {
        int nn = n0 + tid;
        sdis[tid] = dis[nn < NN ? nn : NN - 1];
    }
    constexpr int FQ = K / 4;
    for (int f = tid; f < 64 * FQ; f += 256) {
        int node = f / FQ, kq = f % FQ;
        int nn = n0 + node;
        if (nn < NN) {
            float4 xv = *reinterpret_cast<const float4*>(x + (size_t)nn * K + kq * 4);
            unsigned short* p = &xb[node * XP + kq * 4];
            p[0] = f2bf(xv.x);
            p[1] = f2bf(xv.y);
            p[2] = f2bf(xv.z);
            p[3] = f2bf(xv.w);
        }
    }
    __syncthreads();
    int w = tid >> 6, l = tid & 63;
    int arow = l & 15, kg = l >> 4;
    f32x4 acc0 = {0.f, 0.f, 0.f, 0.f};
    f32x4 acc1 = {0.f, 0.f, 0.f, 0.f};
#pragma unroll
    for (int ks = 0; ks < K / 32; ++ks) {
        short8 a  = *reinterpret_cast<const short8*>(&xb[(w * 16 + arow) * XP + ks * 32 + kg * 8]);
        short8 b0 = *reinterpret_cast<const short8*>(&wt[arow * XP + ks * 32 + kg * 8]);
        short8 b1 = *reinterpret_cast<const short8*>(&wt[(16 + arow) * XP + ks * 32 + kg * 8]);
        acc0 = __builtin_amdgcn_mfma_f32_16x16x32_bf16(a, b0, acc0, 0, 0, 0);
        acc1 = __builtin_amdgcn_mfma_f32_16x16x32_bf16(a, b1, acc1, 0, 0, 0);
    }
#pragma unroll
    for (int r = 0; r < 4; ++r) {
        int nloc = w * 16 + kg * 4 + r;
        int nn = n0 + nloc;
        if (nn < NN) {
            float d = sdis[nloc];
            hs[(size_t)nn * HD + arow]      = f2bf(acc0[r] * d);
            hs[(size_t)nn * HD + 16 + arow] = f2bf(acc1[r] * d);
        }
    }
}

// ---------------- fused gather (+bias/relu[/LN][/next-layer GEMM]) ----------------
// 1-wave blocks (8 nodes) for fine-grained scheduling / straggler backfill.

#define G4(si) \
    { \
        uint2 g0 = *reinterpret_cast<const uint2*>(h + (size_t)(si).x * HD + c0); \
        uint2 g1 = *reinterpret_cast<const uint2*>(h + (size_t)(si).y * HD + c0); \
        uint2 g2 = *reinterpret_cast<const uint2*>(h + (size_t)(si).z * HD + c0); \
        uint2 g3 = *reinterpret_cast<const uint2*>(h + (size_t)(si).w * HD + c0); \
        addpk(a0, a1, g0.x); addpk(a2, a3, g0.y); \
        addpk(a0, a1, g1.x); addpk(a2, a3, g1.y); \
        addpk(a0, a1, g2.x); addpk(a2, a3, g2.y); \
        addpk(a0, a1, g3.x); addpk(a2, a3, g3.y); \
    }

template <int DO_LN, int DO_GEMM>
__global__ __launch_bounds__(GBS) void k_gather(
        const int* __restrict__ row_ptr, const int* __restrict__ csr_src,
        const float* __restrict__ dis, const unsigned short* __restrict__ h,
        const float* __restrict__ bias, const float* __restrict__ g,
        const float* __restrict__ bln, const float* __restrict__ Wn,
        float* __restrict__ outf, unsigned short* __restrict__ outh) {
    __shared__ float sW[HD * HD];  // only used when DO_GEMM
    if (DO_GEMM) {
        for (int t = threadIdx.x; t < HD * HD; t += GBS) sW[t] = Wn[t];
        __syncthreads();  // before any divergence/return
    }
    int idx = blockIdx.x * GBS + threadIdx.x;
    int n = idx >> 3, sub = idx & 7;
    if (n >= NN) return;
    int c0 = sub << 2;

    uint2 u = *reinterpret_cast<const uint2*>(h + (size_t)n * HD + c0);  // self-loop
    float a0 = 0.f, a1 = 0.f, a2 = 0.f, a3 = 0.f;
    addpk(a0, a1, u.x);
    addpk(a2, a3, u.y);

    int e = row_ptr[n], end = row_ptr[n + 1];
    while (e < end && (e & 3)) {
        int s = csr_src[e];
        uint2 hv = *reinterpret_cast<const uint2*>(h + (size_t)s * HD + c0);
        addpk(a0, a1, hv.x);
        addpk(a2, a3, hv.y);
        ++e;
    }
    for (; e + 15 < end; e += 16) {
        int4 s0 = *reinterpret_cast<const int4*>(csr_src + e);
        int4 s1 = *reinterpret_cast<const int4*>(csr_src + e + 4);
        int4 s2 = *reinterpret_cast<const int4*>(csr_src + e + 8);
        int4 s3 = *reinterpret_cast<const int4*>(csr_src + e + 12);
        uint2 g0 = *reinterpret_cast<const uint2*>(h + (size_t)s0.x * HD + c0);
        uint2 g1 = *reinterpret_cast<const uint2*>(h + (size_t)s0.y * HD + c0);
        uint2 g2 = *reinterpret_cast<const uint2*>(h + (size_t)s0.z * HD + c0);
        uint2 g3 = *reinterpret_cast<const uint2*>(h + (size_t)s0.w * HD + c0);
        uint2 g4 = *reinterpret_cast<const uint2*>(h + (size_t)s1.x * HD + c0);
        uint2 g5 = *reinterpret_cast<const uint2*>(h + (size_t)s1.y * HD + c0);
        uint2 g6 = *reinterpret_cast<const uint2*>(h + (size_t)s1.z * HD + c0);
        uint2 g7 = *reinterpret_cast<const uint2*>(h + (size_t)s1.w * HD + c0);
        uint2 g8 = *reinterpret_cast<const uint2*>(h + (size_t)s2.x * HD + c0);
        uint2 g9 = *reinterpret_cast<const uint2*>(h + (size_t)s2.y * HD + c0);
        uint2 ga = *reinterpret_cast<const uint2*>(h + (size_t)s2.z * HD + c0);
        uint2 gb = *reinterpret_cast<const uint2*>(h + (size_t)s2.w * HD + c0);
        uint2 gc = *reinterpret_cast<const uint2*>(h + (size_t)s3.x * HD + c0);
        uint2 gd = *reinterpret_cast<const uint2*>(h + (size_t)s3.y * HD + c0);
        uint2 ge = *reinterpret_cast<const uint2*>(h + (size_t)s3.z * HD + c0);
        uint2 gf = *reinterpret_cast<const uint2*>(h + (size_t)s3.w * HD + c0);
        addpk(a0, a1, g0.x); addpk(a2, a3, g0.y);
        addpk(a0, a1, g1.x); addpk(a2, a3, g1.y);
        addpk(a0, a1, g2.x); addpk(a2, a3, g2.y);
        addpk(a0, a1, g3.x); addpk(a2, a3, g3.y);
        addpk(a0, a1, g4.x); addpk(a2, a3, g4.y);
        addpk(a0, a1, g5.x); addpk(a2, a3, g5.y);
        addpk(a0, a1, g6.x); addpk(a2, a3, g6.y);
        addpk(a0, a1, g7.x); addpk(a2, a3, g7.y);
        addpk(a0, a1, g8.x); addpk(a2, a3, g8.y);
        addpk(a0, a1, g9.x); addpk(a2, a3, g9.y);
        addpk(a0, a1, ga.x); addpk(a2, a3, ga.y);
        addpk(a0, a1, gb.x); addpk(a2, a3, gb.y);
        addpk(a0, a1, gc.x); addpk(a2, a3, gc.y);
        addpk(a0, a1, gd.x); addpk(a2, a3, gd.y);
        addpk(a0, a1, ge.x); addpk(a2, a3, ge.y);
        addpk(a0, a1, gf.x); addpk(a2, a3, gf.y);
    }
    if (e + 7 < end) {
        int4 s0 = *reinterpret_cast<const int4*>(csr_src + e);
        int4 s1 = *reinterpret_cast<const int4*>(csr_src + e + 4);
        G4(s0);
        G4(s1);
        e += 8;
    }
    if (e + 3 < end) {
        int4 s0 = *reinterpret_cast<const int4*>(csr_src + e);
        G4(s0);
        e += 4;
    }
    for (; e < end; ++e) {
        int s = csr_src[e];
        uint2 hv = *reinterpret_cast<const uint2*>(h + (size_t)s * HD + c0);
        addpk(a0, a1, hv.x);
        addpk(a2, a3, hv.y);
    }

    float d = dis[n];
    float4 bv = *reinterpret_cast<const float4*>(bias + c0);
    float v0 = fmaxf(fmaf(a0, d, bv.x), 0.f);
    float v1 = fmaxf(fmaf(a1, d, bv.y), 0.f);
    float v2 = fmaxf(fmaf(a2, d, bv.z), 0.f);
    float v3 = fmaxf(fmaf(a3, d, bv.w), 0.f);

    if (DO_LN) {
        float s = (v0 + v1) + (v2 + v3);
        float s2 = (v0 * v0 + v1 * v1) + (v2 * v2 + v3 * v3);
#pragma unroll
        for (int m = 4; m >= 1; m >>= 1) {
            s += __shfl_xor(s, m, 8);
            s2 += __shfl_xor(s2, m, 8);
        }
        float mean = s * (1.f / 32.f);
        float var = s2 * (1.f / 32.f) - mean * mean;
        float r = rsqrtf(var + LN_EPS);
        float4 gv = *reinterpret_cast<const float4*>(g + c0);
        float4 lb = *reinterpret_cast<const float4*>(bln + c0);
        v0 = (v0 - mean) * r * gv.x + lb.x;
        v1 = (v1 - mean) * r * gv.y + lb.y;
        v2 = (v2 - mean) * r * gv.z + lb.z;
        v3 = (v3 - mean) * r * gv.w + lb.w;
    }

    if (DO_GEMM) {
        float y0 = 0.f, y1 = 0.f, y2 = 0.f, y3 = 0.f;
#pragma unroll
        for (int m = 0; m < 8; ++m) {
            float vk0 = __shfl(v0, m, 8);  // channel 4m+0
            float vk1 = __shfl(v1, m, 8);
            float vk2 = __shfl(v2, m, 8);
            float vk3 = __shfl(v3, m, 8);
            float4 w0 = *reinterpret_cast<const float4*>(&sW[(4 * m + 0) * HD + c0]);
            float4 w1 = *reinterpret_cast<const float4*>(&sW[(4 * m + 1) * HD + c0]);
            float4 w2 = *reinterpret_cast<const float4*>(&sW[(4 * m + 2) * HD + c0]);
            float4 w3 = *reinterpret_cast<const float4*>(&sW[(4 * m + 3) * HD + c0]);
            y0 = fmaf(vk0, w0.x, fmaf(vk1, w1.x, fmaf(vk2, w2.x, fmaf(vk3, w3.x, y0))));
            y1 = fmaf(vk0, w0.y, fmaf(vk1, w1.y, fmaf(vk2, w2.y, fmaf(vk3, w3.y, y1))));
            y2 = fmaf(vk0, w0.z, fmaf(vk1, w1.z, fmaf(vk2, w2.z, fmaf(vk3, w3.z, y2))));
            y3 = fmaf(vk0, w0.w, fmaf(vk1, w1.w, fmaf(vk2, w2.w, fmaf(vk3, w3.w, y3))));
        }
        uint2 pp;
        pp.x = pack2(y0 * d, y1 * d);
        pp.y = pack2(y2 * d, y3 * d);
        *reinterpret_cast<uint2*>(outh + (size_t)n * HD + c0) = pp;
    } else {
        float4_v ov;
        ov[0] = v0; ov[1] = v1; ov[2] = v2; ov[3] = v3;
        __builtin_nontemporal_store(ov, reinterpret_cast<float4_v*>(outf + (size_t)n * HD + c0));
    }
}

// ---------------- final: MLP head + log_softmax ----------------

__global__ void k_final(const float* __restrict__ hin,
                        const float* __restrict__ w1, const float* __restrict__ mb1,
                        const float* __restrict__ w2, const float* __restrict__ mb2,
                        float* __restrict__ out) {
    __shared__ float sw1[HD * MID], sw2[MID * OUTD], sb1[MID], sb2[OUTD];
    for (int t = threadIdx.x; t < HD * MID; t += blockDim.x) sw1[t] = w1[t];
    for (int t = threadIdx.x; t < MID * OUTD; t += blockDim.x) sw2[t] = w2[t];
    if (threadIdx.x < MID) sb1[threadIdx.x] = mb1[threadIdx.x];
    if (threadIdx.x < OUTD) sb2[threadIdx.x] = mb2[threadIdx.x];
    __syncthreads();
    int n = blockIdx.x * blockDim.x + threadIdx.x;
    if (n >= NN) return;
    float h[HD];
    const float* ar = hin + (size_t)n * HD;
#pragma unroll
    for (int k = 0; k < HD; ++k) h[k] = ar[k];
    float t[MID];
#pragma unroll
    for (int j = 0; j < MID; ++j) {
        float a = sb1[j];
#pragma unroll
        for (int k = 0; k < HD; ++k) a += h[k] * sw1[k * MID + j];
        t[j] = fmaxf(a, 0.f);
    }
    float o[OUTD];
#pragma unroll
    for (int j = 0; j < OUTD; ++j) {
        float a = sb2[j];
#pragma unroll
        for (int k = 0; k < MID; ++k) a += t[k] * sw2[k * OUTD + j];
        o[j] = a;
    }
    float mx = o[0];
#pragma unroll
    for (int j = 1; j < OUTD; ++j) mx = fmaxf(mx, o[j]);
    float se = 0.f;
#pragma unroll
    for (int j = 0; j < OUTD; ++j) se += __expf(o[j] - mx);
    float lse = __logf(se) + mx;
    float* orow = out + (size_t)n * OUTD;
#pragma unroll
    for (int j = 0; j < OUTD; ++j) orow[j] = o[j] - lse;
}

// ---------------- launch ----------------

extern "C" void kernel_launch(void* const* d_in, const int* in_sizes, int n_in,
                              void* d_out, int out_size, void* d_ws, size_t ws_size,
                              hipStream_t stream) {
    const float* x     = (const float*)d_in[0];
    const int*   ei    = (const int*)d_in[1];
    const float* W0    = (const float*)d_in[2];
    const float* b0    = (const float*)d_in[3];
    const float* W1    = (const float*)d_in[4];
    const float* b1    = (const float*)d_in[5];
    const float* W2    = (const float*)d_in[6];
    const float* b2    = (const float*)d_in[7];
    const float* ln0_g = (const float*)d_in[8];
    const float* ln0_b = (const float*)d_in[9];
    const float* ln1_g = (const float*)d_in[10];
    const float* ln1_b = (const float*)d_in[11];
    const float* mp_w1 = (const float*)d_in[12];
    const float* mp_b1 = (const float*)d_in[13];
    const float* mp_w2 = (const float*)d_in[14];
    const float* mp_b2 = (const float*)d_in[15];
    float* out = (float*)d_out;

    const int* src = ei;        // edge_index[0]
    const int* dst = ei + NE;   // edge_index[1]

    char* w = (char*)d_ws;
    auto align256 = [](size_t v) { return (v + 255) & ~(size_t)255; };
    int* g_bincur  = (int*)w;   w += align256((size_t)NB * 4);
    int* g_binexcl = (int*)w;   w += align256((size_t)NB * 4);
    int* row_ptr   = (int*)w;   w += align256((size_t)(NN + 1) * 4);
    float* dis     = (float*)w; w += align256((size_t)NN * 4);
    char* uni = w;              // union region (staging vs activations)
    size_t hs_sz = align256((size_t)NN * HD * 2);
    unsigned short* hs0 = (unsigned short*)uni;                 // bf16, 6.4 MB
    unsigned short* hs1 = (unsigned short*)(uni + hs_sz);       // bf16, 6.4 MB
    float* bufA = (float*)(uni + 2 * hs_sz);                    // f32, 12.8 MB
    unsigned int* staged = (unsigned int*)uni;                  // 16.0 MB (build only)
    size_t uni_sz = align256((size_t)NB * CAP * 4);
    size_t uni_sz2 = 2 * hs_sz + align256((size_t)NN * HD * 4);
    w = uni + (uni_sz > uni_sz2 ? uni_sz : uni_sz2);
    int* csr_src = (int*)w;

    const int BS = 256;
    int gN  = (NN + BS - 1) / BS;            // 391
    int gA  = (NE + EPB - 1) / EPB;          // 391
    int gW  = (NN * 8 + GBS - 1) / GBS;      // 12500 (1-wave gather blocks)
    int gG  = (NN + 63) / 64;                // 1563

    // CSR build (binned counting sort)
    k_zero_bins<<<1, 512, 0, stream>>>(g_bincur);
    k_binA<<<gA, ABS, 0, stream>>>(src, dst, g_bincur, staged);
    k_binscan<<<1, 512, 0, stream>>>(g_bincur, g_binexcl, row_ptr);
    k_binC<<<NB, CBS, 0, stream>>>(g_bincur, g_binexcl, staged, row_ptr, dis, csr_src);

    // layer 0 GEMM (MFMA) -> hs0
    k_gemm_mfma<DIN><<<gG, BS, 0, stream>>>(x, W0, dis, hs0);
    // layer 0 gather + LN + layer-1 GEMM fused -> hs1
    k_gather<1, 1><<<gW, GBS, 0, stream>>>(row_ptr, csr_src, dis, hs0, b0,
                                           ln0_g, ln0_b, W1, nullptr, hs1);
    // layer 1 gather + LN + layer-2 GEMM fused -> hs0
    k_gather<1, 1><<<gW, GBS, 0, stream>>>(row_ptr, csr_src, dis, hs1, b1,
                                           ln1_g, ln1_b, W2, nullptr, hs0);
    // layer 2 gather (no LN, no GEMM) -> bufA f32
    k_gather<0, 0><<<gW, GBS, 0, stream>>>(row_ptr, csr_src, dis, hs0, b2,
                                           nullptr, nullptr, nullptr, bufA, nullptr);

    // head
    k_final<<<gN, BS, 0, stream>>>(bufA, mp_w1, mp_b1, mp_w2, mp_b2, out);
}